// Round 1
// baseline (95091.461 us; speedup 1.0000x reference)
//
#include <hip/hip_runtime.h>
#include <math.h>

#define T_STEPS 512
#define BATCH   128
#define HDIM    300
#define M       20

// ---------------- JAX threefry2x32 noise replication ----------------
__device__ __forceinline__ unsigned rotl32(unsigned v, int r) {
    return (v << r) | (v >> (32 - r));
}

__device__ float jax_noise(unsigned i) {
#pragma clang fp contract(off)
    unsigned x0 = 0u;
    unsigned x1 = i;
    const unsigned ks0 = 0u, ks1 = 42u, ks2 = 0u ^ 42u ^ 0x1BD11BDAu;
    x0 += ks0; x1 += ks1;
    x0 += x1; x1 = rotl32(x1, 13); x1 ^= x0;
    x0 += x1; x1 = rotl32(x1, 15); x1 ^= x0;
    x0 += x1; x1 = rotl32(x1, 26); x1 ^= x0;
    x0 += x1; x1 = rotl32(x1, 6);  x1 ^= x0;
    x0 += ks1; x1 += ks2 + 1u;
    x0 += x1; x1 = rotl32(x1, 17); x1 ^= x0;
    x0 += x1; x1 = rotl32(x1, 29); x1 ^= x0;
    x0 += x1; x1 = rotl32(x1, 16); x1 ^= x0;
    x0 += x1; x1 = rotl32(x1, 24); x1 ^= x0;
    x0 += ks2; x1 += ks0 + 2u;
    x0 += x1; x1 = rotl32(x1, 13); x1 ^= x0;
    x0 += x1; x1 = rotl32(x1, 15); x1 ^= x0;
    x0 += x1; x1 = rotl32(x1, 26); x1 ^= x0;
    x0 += x1; x1 = rotl32(x1, 6);  x1 ^= x0;
    x0 += ks0; x1 += ks1 + 3u;
    x0 += x1; x1 = rotl32(x1, 17); x1 ^= x0;
    x0 += x1; x1 = rotl32(x1, 29); x1 ^= x0;
    x0 += x1; x1 = rotl32(x1, 16); x1 ^= x0;
    x0 += x1; x1 = rotl32(x1, 24); x1 ^= x0;
    x0 += ks1; x1 += ks2 + 4u;
    x0 += x1; x1 = rotl32(x1, 13); x1 ^= x0;
    x0 += x1; x1 = rotl32(x1, 15); x1 ^= x0;
    x0 += x1; x1 = rotl32(x1, 26); x1 ^= x0;
    x0 += x1; x1 = rotl32(x1, 6);  x1 ^= x0;
    x0 += ks2; x1 += ks0 + 5u;

    const unsigned bits = x0 ^ x1;
    const unsigned fb = (bits >> 9) | 0x3f800000u;
    float f = __uint_as_float(fb) - 1.0f;
    const float span = 1.0f - 0.01f;
    float v = f * span;
    v = v + 0.01f;
    return fmaxf(0.01f, v);
}

// ---------------- main persistent per-batch kernel ----------------
// grid = 128 blocks (one per batch element), 640 threads = 10 waves.
// Phase A (GEMVs): threads 0-319 -> hb1/ent columns; 320-639 -> hwu columns.
// Phase B (big GEMMs): thread = (k-slice s = tid/160, column-pair p = tid%160).
//   Each thread computes BOTH sim and cand partials for 2 columns over 1/4 of K,
//   so each sh_mem broadcast read feeds 16 FMAs (vs 4 before) -> ~4x fewer LDS instrs.
__global__ void __launch_bounds__(640)
wm_kernel(const float* __restrict__ hs,   // (T,B,H)
          const float* __restrict__ msk,  // (T,B)
          const float* __restrict__ We1,  // (300,300)
          const float* __restrict__ be1,  // (300)
          const float* __restrict__ We2,  // (300,1)
          const float* __restrict__ be2,  // (1)
          const float* __restrict__ Ws1,  // (901,300)
          const float* __restrict__ bs1,  // (300)
          const float* __restrict__ Ws2,  // (300,1)
          const float* __restrict__ bs2,  // (1)
          const float* __restrict__ Wu,   // (600,300)
          const float* __restrict__ bu,   // (300)
          float* __restrict__ out)
{
    __shared__ __align__(16) float sh_mem[M][HDIM];
    __shared__ __align__(16) float sh_h[HDIM];
    __shared__ __align__(16) float sh_sim[M][HDIM];   // sim slice-reduction buffer
    __shared__ __align__(16) float sh_cand[M][HDIM];  // cand slice-reduction buffer
    __shared__ __align__(16) float sh_usage[M];
    __shared__ float sh_simpart[5][M];
    __shared__ float sh_entpart[5];
    __shared__ float sh_ow[M];
    __shared__ float sh_indv[M];

    const int b    = blockIdx.x;
    const int tid  = threadIdx.x;
    const int wave = tid >> 6;   // 0..9
    const int lane = tid & 63;

    // ---- Phase A / sim-finish / Phase D mapping ----
    const bool lower = tid < 320;
    const int cA     = lower ? tid : (tid - 320);
    const bool actA  = cA < HDIM;

    // ---- Phase B mapping: 4 k-slices x 150 column-pairs ----
    const int  s    = tid / 160;          // k-slice 0..3
    const int  p    = tid % 160;          // column-pair
    const bool actB = p < 150;
    const int  c0   = 2 * p;              // columns c0, c0+1
    const int  kbeg = s * 76;
    const int  kend = (s == 3) ? 300 : (kbeg + 76);   // slices: 76,76,76,72

    // ---- init state ----
    for (int idx = tid; idx < M * HDIM; idx += 640) ((float*)sh_mem)[idx] = 0.0f;
    if (tid < M) sh_usage[tid] = 0.0f;

    const float be2v = be2[0];
    const float bs2v = bs2[0];
    // step-invariant per-column scalars
    float bs1c = 0.f, be1c = 0.f, we2c = 0.f, ws2c = 0.f, w900c = 0.f, buc = 0.f;
    if (actA) {
        if (lower) {
            bs1c = bs1[cA]; be1c = be1[cA]; we2c = We2[cA];
            ws2c = Ws2[cA]; w900c = Ws1[900 * 300 + cA];
        } else {
            buc = bu[cA];
        }
    }
    __syncthreads();

    for (int t = 0; t < T_STEPS; ++t) {
        const int tb = t * BATCH + b;

        // ---- load h (upper half) ----
        if (!lower && actA) sh_h[cA] = hs[(size_t)tb * HDIM + cA];
        __syncthreads();   // (1) h ready; prev step fully done

        // ---- Phase A: h-GEMVs (hb1, hwu in registers; ent partials) ----
        float hb1reg = 0.f, hwureg = 0.f;
        {
            float a1 = 0.f, ae = 0.f, au = 0.f;
            if (actA) {
                if (lower) {
                    const float* pB = Ws1 + 90000 + cA;   // rows 300..599
                    const float* pE = We1 + cA;
                    for (int k = 0; k < HDIM; k += 4) {
                        float4 h4 = *(const float4*)&sh_h[k];
                        const float* q  = pB + k * 300;
                        const float* qe = pE + k * 300;
                        a1 += h4.x * q[0] + h4.y * q[300] + h4.z * q[600] + h4.w * q[900];
                        ae += h4.x * qe[0] + h4.y * qe[300] + h4.z * qe[600] + h4.w * qe[900];
                    }
                } else {
                    const float* pU = Wu + cA;            // rows 0..299
                    for (int k = 0; k < HDIM; k += 4) {
                        float4 h4 = *(const float4*)&sh_h[k];
                        const float* q = pU + k * 300;
                        au += h4.x * q[0] + h4.y * q[300] + h4.z * q[600] + h4.w * q[900];
                    }
                }
            }
            if (lower) {
                float er = actA ? (fmaxf(ae + be1c, 0.0f) * we2c) : 0.0f;
                for (int off = 32; off; off >>= 1) er += __shfl_xor(er, off, 64);
                if (lane == 0) sh_entpart[wave] = er;
                hb1reg = a1 + bs1c;
            } else {
                hwureg = au + buc;
            }
        }

        // ---- Phase B: fused sim+cand K-slice loop, 2 columns per thread ----
        float aS0[M], aS1[M], aC0[M], aC1[M];
#pragma unroll
        for (int j = 0; j < M; ++j) { aS0[j] = 0.f; aS1[j] = 0.f; aC0[j] = 0.f; aC1[j] = 0.f; }

        if (actB) {
            const float* pA = Ws1 + c0;            // rows 0..299   (mem)
            const float* pC = Ws1 + 180000 + c0;   // rows 600..899 (h*mem)
            const float* pU = Wu + 90000 + c0;     // rows 300..599 (mem)
            for (int k = kbeg; k < kend; k += 4) {
                float4 h4 = *(const float4*)&sh_h[k];
                const float* qa = pA + k * 300;
                const float* qc = pC + k * 300;
                const float* qu = pU + k * 300;
                float w00 = fmaf(h4.x, qc[0],   qa[0]);
                float w01 = fmaf(h4.y, qc[300], qa[300]);
                float w02 = fmaf(h4.z, qc[600], qa[600]);
                float w03 = fmaf(h4.w, qc[900], qa[900]);
                float w10 = fmaf(h4.x, qc[1],   qa[1]);
                float w11 = fmaf(h4.y, qc[301], qa[301]);
                float w12 = fmaf(h4.z, qc[601], qa[601]);
                float w13 = fmaf(h4.w, qc[901], qa[901]);
                float u00 = qu[0], u01 = qu[300], u02 = qu[600], u03 = qu[900];
                float u10 = qu[1], u11 = qu[301], u12 = qu[601], u13 = qu[901];
#pragma unroll
                for (int j = 0; j < M; ++j) {
                    float4 mv = *(const float4*)&sh_mem[j][k];
                    aS0[j] += mv.x * w00 + mv.y * w01 + mv.z * w02 + mv.w * w03;
                    aS1[j] += mv.x * w10 + mv.y * w11 + mv.z * w12 + mv.w * w13;
                    aC0[j] += mv.x * u00 + mv.y * u01 + mv.z * u02 + mv.w * u03;
                    aC1[j] += mv.x * u10 + mv.y * u11 + mv.z * u12 + mv.w * u13;
                }
            }
        }
        // slice 0 writes its partials (exclusive owner of its column pair)
        if (actB && s == 0) {
#pragma unroll
            for (int j = 0; j < M; ++j) {
                *(float2*)&sh_sim[j][c0]  = make_float2(aS0[j], aS1[j]);
                *(float2*)&sh_cand[j][c0] = make_float2(aC0[j], aC1[j]);
            }
        }
        __syncthreads();   // (2)
        if (actB && s != 0) {
#pragma unroll
            for (int j = 0; j < M; ++j) {
                atomicAdd(&sh_sim[j][c0],      aS0[j]);
                atomicAdd(&sh_sim[j][c0 + 1],  aS1[j]);
                atomicAdd(&sh_cand[j][c0],     aC0[j]);
                atomicAdd(&sh_cand[j][c0 + 1], aC1[j]);
            }
        }
        __syncthreads();   // (3)

        // ---- sim finish: relu(.)*Ws2, reduce over columns (lower waves) ----
        if (lower) {
            float usg[M];
#pragma unroll
            for (int j = 0; j < M; j += 4) {
                float4 u4 = *(const float4*)&sh_usage[j];
                usg[j] = u4.x; usg[j+1] = u4.y; usg[j+2] = u4.z; usg[j+3] = u4.w;
            }
#pragma unroll
            for (int j = 0; j < M; ++j) {
                float v = 0.f;
                if (actA) {
                    float pre = sh_sim[j][cA] + hb1reg + usg[j] * w900c;
                    v = fmaxf(pre, 0.0f) * ws2c;
                }
                for (int off = 32; off; off >>= 1) v += __shfl_xor(v, off, 64);
                if (lane == 0) sh_simpart[wave][j] = v;
            }
        }
        __syncthreads();   // (4)

        // ---- Phase C: decision (wave 0) ----
        if (wave == 0) {
            const bool act = lane < M;
            float simj = -INFINITY, usg = 0.0f;
            if (act) {
                float sv = sh_simpart[0][lane];
                sv += sh_simpart[1][lane];
                sv += sh_simpart[2][lane];
                sv += sh_simpart[3][lane];
                sv += sh_simpart[4][lane];
                simj = sv + bs2v;
                usg = sh_usage[lane];
            }
            float es = sh_entpart[0] + sh_entpart[1] + sh_entpart[2]
                     + sh_entpart[3] + sh_entpart[4] + be2v;
            const float entp = (1.0f / (1.0f + expf(-es))) * msk[tb];

            const float coref = (act && usg > 0.0f) ? 1.0f : 0.0f;
            float comb = act ? ((usg > 0.0f) ? simj : -10000.0f) : -INFINITY;
            float mx = comb;
            for (int off = 32; off; off >>= 1) mx = fmaxf(mx, __shfl_xor(mx, off, 64));
            mx = fmaxf(mx, 0.0f);
            float e = act ? expf(comb - mx) : 0.0f;
            const float eM = expf(0.0f - mx);
            float den = e;
            for (int off = 32; off; off >>= 1) den += __shfl_xor(den, off, 64);
            den += eM;
            const float prob  = e / den;
            const float probM = eM / den;
            float masked = prob * coref;
            float msum = masked;
            for (int off = 32; off; off >>= 1) msum += __shfl_xor(msum, off, 64);
            msum += probM;
            const float dn = msum + 1e-8f;
            const float normj = masked / dn;
            const float normM = probM / dn;
            const float indv = act ? (entp * normj) : 0.0f;
            const float ow_base = entp * normM;

            // nsim = softmax(sim)
            float nmx = simj;
            for (int off = 32; off; off >>= 1) nmx = fmaxf(nmx, __shfl_xor(nmx, off, 64));
            float ne = act ? expf(simj - nmx) : 0.0f;
            float ns = ne;
            for (int off = 32; off; off >>= 1) ns += __shfl_xor(ns, off, 64);
            const float nsim = ne / ns;

            float ows = act ? (((usg == 0.0f) ? nsim * 100000.0f : 0.0f) + (1.0f - usg))
                            : -INFINITY;
            float mv = ows;
            for (int off = 32; off; off >>= 1) mv = fmaxf(mv, __shfl_xor(mv, off, 64));

            float key = 0.0f;
            if (act && ows == mv) key = jax_noise((unsigned)(tb * M + lane));
            float bv = act ? key : -1.0f;
            int bi = act ? lane : 1023;
            for (int off = 32; off; off >>= 1) {
                float ov = __shfl_xor(bv, off, 64);
                int oi = __shfl_xor(bi, off, 64);
                if (ov > bv || (ov == bv && oi < bi)) { bv = ov; bi = oi; }
            }
            const float ow = (act && lane == bi) ? ow_base : 0.0f;
            const float nu = fminf(1.0f, (ow + indv) + 0.98f * usg);

            if (act) {
                sh_ow[lane] = ow;
                sh_indv[lane] = indv;
                sh_usage[lane] = nu;
                const int base = tb * M + lane;
                out[65536 + base]   = nu;                                   // usage_seq
                out[1376256 + base] = indv * (1.0f - 1e-8f) + 1e-8f;        // coref
                out[2686976 + base] = ow * (1.0f - 1e-8f) + 1e-8f;          // overwrite
            }
            if (lane == 0) out[tb] = entp * (1.0f - 1e-8f) + 1e-8f;          // ent
        }
        __syncthreads();   // (5)

        // ---- Phase D: memory update (upper half; cand = tanh(sum + hwu)) ----
        if (!lower && actA) {
            const float hc = sh_h[cA];
#pragma unroll
            for (int j = 0; j < M; ++j) {
                const float owj = sh_ow[j];
                const float inj = sh_indv[j];
                const float cd  = tanhf(sh_cand[j][cA] + hwureg);
                const float mo  = sh_mem[j][cA];
                sh_mem[j][cA] = owj * hc + (1.0f - owj - inj) * mo + inj * cd;
            }
        }
        __syncthreads();   // (6)
    }
}

extern "C" void kernel_launch(void* const* d_in, const int* in_sizes, int n_in,
                              void* d_out, int out_size, void* d_ws, size_t ws_size,
                              hipStream_t stream) {
    (void)in_sizes; (void)n_in; (void)d_ws; (void)ws_size; (void)out_size;
    const float* hs  = (const float*)d_in[0];
    const float* msk = (const float*)d_in[1];
    const float* We1 = (const float*)d_in[2];
    const float* be1 = (const float*)d_in[3];
    const float* We2 = (const float*)d_in[4];
    const float* be2 = (const float*)d_in[5];
    const float* Ws1 = (const float*)d_in[6];
    const float* bs1 = (const float*)d_in[7];
    const float* Ws2 = (const float*)d_in[8];
    const float* bs2 = (const float*)d_in[9];
    const float* Wu  = (const float*)d_in[10];
    const float* bu  = (const float*)d_in[11];
    float* out = (float*)d_out;

    hipLaunchKernelGGL(wm_kernel, dim3(BATCH), dim3(640), 0, stream,
                       hs, msk, We1, be1, We2, be2, Ws1, bs1, Ws2, bs2, Wu, bu, out);
}

// Round 2
// 93342.383 us; speedup vs baseline: 1.0187x; 1.0187x over previous
//
#include <hip/hip_runtime.h>
#include <math.h>

#define T_STEPS 512
#define BATCH   128
#define HDIM    300
#define M       20

// ---------------- JAX threefry2x32 noise replication ----------------
__device__ __forceinline__ unsigned rotl32(unsigned v, int r) {
    return (v << r) | (v >> (32 - r));
}

__device__ float jax_noise(unsigned i) {
#pragma clang fp contract(off)
    unsigned x0 = 0u;
    unsigned x1 = i;
    const unsigned ks0 = 0u, ks1 = 42u, ks2 = 0u ^ 42u ^ 0x1BD11BDAu;
    x0 += ks0; x1 += ks1;
    x0 += x1; x1 = rotl32(x1, 13); x1 ^= x0;
    x0 += x1; x1 = rotl32(x1, 15); x1 ^= x0;
    x0 += x1; x1 = rotl32(x1, 26); x1 ^= x0;
    x0 += x1; x1 = rotl32(x1, 6);  x1 ^= x0;
    x0 += ks1; x1 += ks2 + 1u;
    x0 += x1; x1 = rotl32(x1, 17); x1 ^= x0;
    x0 += x1; x1 = rotl32(x1, 29); x1 ^= x0;
    x0 += x1; x1 = rotl32(x1, 16); x1 ^= x0;
    x0 += x1; x1 = rotl32(x1, 24); x1 ^= x0;
    x0 += ks2; x1 += ks0 + 2u;
    x0 += x1; x1 = rotl32(x1, 13); x1 ^= x0;
    x0 += x1; x1 = rotl32(x1, 15); x1 ^= x0;
    x0 += x1; x1 = rotl32(x1, 26); x1 ^= x0;
    x0 += x1; x1 = rotl32(x1, 6);  x1 ^= x0;
    x0 += ks0; x1 += ks1 + 3u;
    x0 += x1; x1 = rotl32(x1, 17); x1 ^= x0;
    x0 += x1; x1 = rotl32(x1, 29); x1 ^= x0;
    x0 += x1; x1 = rotl32(x1, 16); x1 ^= x0;
    x0 += x1; x1 = rotl32(x1, 24); x1 ^= x0;
    x0 += ks1; x1 += ks2 + 4u;
    x0 += x1; x1 = rotl32(x1, 13); x1 ^= x0;
    x0 += x1; x1 = rotl32(x1, 15); x1 ^= x0;
    x0 += x1; x1 = rotl32(x1, 26); x1 ^= x0;
    x0 += x1; x1 = rotl32(x1, 6);  x1 ^= x0;
    x0 += ks2; x1 += ks0 + 5u;

    const unsigned bits = x0 ^ x1;
    const unsigned fb = (bits >> 9) | 0x3f800000u;
    float f = __uint_as_float(fb) - 1.0f;
    const float span = 1.0f - 0.01f;
    float v = f * span;
    v = v + 0.01f;
    return fmaxf(0.01f, v);
}

// ---------------- main persistent per-batch kernel ----------------
// grid = 128 blocks (one per batch element), 640 threads = 10 waves.
// __launch_bounds__(640, 3): 3 waves/SIMD worst case (10 waves, 1 block/CU)
//   -> VGPR cap ~168, enough for the 80-float accumulator block WITHOUT
//   scratch spill (R1 failure mode: default cap 84 -> 15.6 GB spill traffic).
// Phase A (GEMVs): threads 0-319 -> hb1/ent columns; 320-639 -> hwu columns.
// Phase B (big GEMMs): thread = (k-slice s = tid/160, column-pair p = tid%160).
//   Each thread computes BOTH sim and cand partials for 2 columns over 1/4 of K,
//   so each sh_mem broadcast read feeds 16 FMAs -> ~4x fewer LDS instrs vs R0.
__global__ void __launch_bounds__(640, 3)
wm_kernel(const float* __restrict__ hs,   // (T,B,H)
          const float* __restrict__ msk,  // (T,B)
          const float* __restrict__ We1,  // (300,300)
          const float* __restrict__ be1,  // (300)
          const float* __restrict__ We2,  // (300,1)
          const float* __restrict__ be2,  // (1)
          const float* __restrict__ Ws1,  // (901,300)
          const float* __restrict__ bs1,  // (300)
          const float* __restrict__ Ws2,  // (300,1)
          const float* __restrict__ bs2,  // (1)
          const float* __restrict__ Wu,   // (600,300)
          const float* __restrict__ bu,   // (300)
          float* __restrict__ out)
{
    __shared__ __align__(16) float sh_mem[M][HDIM];
    __shared__ __align__(16) float sh_h[HDIM];
    __shared__ __align__(16) float sh_sim[M][HDIM];   // sim slice-reduction buffer
    __shared__ __align__(16) float sh_cand[M][HDIM];  // cand slice-reduction buffer
    __shared__ __align__(16) float sh_usage[M];
    __shared__ float sh_simpart[5][M];
    __shared__ float sh_entpart[5];
    __shared__ float sh_ow[M];
    __shared__ float sh_indv[M];

    const int b    = blockIdx.x;
    const int tid  = threadIdx.x;
    const int wave = tid >> 6;   // 0..9
    const int lane = tid & 63;

    // ---- Phase A / sim-finish / Phase D mapping ----
    const bool lower = tid < 320;
    const int cA     = lower ? tid : (tid - 320);
    const bool actA  = cA < HDIM;

    // ---- Phase B mapping: 4 k-slices x 150 column-pairs ----
    const int  s    = tid / 160;          // k-slice 0..3
    const int  p    = tid % 160;          // column-pair
    const bool actB = p < 150;
    const int  c0   = 2 * p;              // columns c0, c0+1
    const int  kbeg = s * 76;
    const int  kend = (s == 3) ? 300 : (kbeg + 76);   // slices: 76,76,76,72

    // ---- init state ----
    for (int idx = tid; idx < M * HDIM; idx += 640) ((float*)sh_mem)[idx] = 0.0f;
    if (tid < M) sh_usage[tid] = 0.0f;

    const float be2v = be2[0];
    const float bs2v = bs2[0];
    // step-invariant per-column scalars
    float bs1c = 0.f, be1c = 0.f, we2c = 0.f, ws2c = 0.f, w900c = 0.f, buc = 0.f;
    if (actA) {
        if (lower) {
            bs1c = bs1[cA]; be1c = be1[cA]; we2c = We2[cA];
            ws2c = Ws2[cA]; w900c = Ws1[900 * 300 + cA];
        } else {
            buc = bu[cA];
        }
    }
    __syncthreads();

    for (int t = 0; t < T_STEPS; ++t) {
        const int tb = t * BATCH + b;

        // ---- load h (upper half) ----
        if (!lower && actA) sh_h[cA] = hs[(size_t)tb * HDIM + cA];
        __syncthreads();   // (1) h ready; prev step fully done

        // ---- Phase A: h-GEMVs (hb1, hwu in registers; ent partials) ----
        float hb1reg = 0.f, hwureg = 0.f;
        {
            float a1 = 0.f, ae = 0.f, au = 0.f;
            if (actA) {
                if (lower) {
                    const float* pB = Ws1 + 90000 + cA;   // rows 300..599
                    const float* pE = We1 + cA;
                    for (int k = 0; k < HDIM; k += 4) {
                        float4 h4 = *(const float4*)&sh_h[k];
                        const float* q  = pB + k * 300;
                        const float* qe = pE + k * 300;
                        a1 += h4.x * q[0] + h4.y * q[300] + h4.z * q[600] + h4.w * q[900];
                        ae += h4.x * qe[0] + h4.y * qe[300] + h4.z * qe[600] + h4.w * qe[900];
                    }
                } else {
                    const float* pU = Wu + cA;            // rows 0..299
                    for (int k = 0; k < HDIM; k += 4) {
                        float4 h4 = *(const float4*)&sh_h[k];
                        const float* q = pU + k * 300;
                        au += h4.x * q[0] + h4.y * q[300] + h4.z * q[600] + h4.w * q[900];
                    }
                }
            }
            if (lower) {
                float er = actA ? (fmaxf(ae + be1c, 0.0f) * we2c) : 0.0f;
                for (int off = 32; off; off >>= 1) er += __shfl_xor(er, off, 64);
                if (lane == 0) sh_entpart[wave] = er;
                hb1reg = a1 + bs1c;
            } else {
                hwureg = au + buc;
            }
        }

        // ---- Phase B: fused sim+cand K-slice loop, 2 columns per thread ----
        float aS0[M], aS1[M], aC0[M], aC1[M];
#pragma unroll
        for (int j = 0; j < M; ++j) { aS0[j] = 0.f; aS1[j] = 0.f; aC0[j] = 0.f; aC1[j] = 0.f; }

        if (actB) {
            const float* pA = Ws1 + c0;            // rows 0..299   (mem)
            const float* pC = Ws1 + 180000 + c0;   // rows 600..899 (h*mem)
            const float* pU = Wu + 90000 + c0;     // rows 300..599 (mem)
#pragma unroll 1
            for (int k = kbeg; k < kend; k += 4) {
                float4 h4 = *(const float4*)&sh_h[k];
                const float* qa = pA + k * 300;
                const float* qc = pC + k * 300;
                const float* qu = pU + k * 300;
                float w00 = fmaf(h4.x, qc[0],   qa[0]);
                float w01 = fmaf(h4.y, qc[300], qa[300]);
                float w02 = fmaf(h4.z, qc[600], qa[600]);
                float w03 = fmaf(h4.w, qc[900], qa[900]);
                float w10 = fmaf(h4.x, qc[1],   qa[1]);
                float w11 = fmaf(h4.y, qc[301], qa[301]);
                float w12 = fmaf(h4.z, qc[601], qa[601]);
                float w13 = fmaf(h4.w, qc[901], qa[901]);
                float u00 = qu[0], u01 = qu[300], u02 = qu[600], u03 = qu[900];
                float u10 = qu[1], u11 = qu[301], u12 = qu[601], u13 = qu[901];
#pragma unroll
                for (int j = 0; j < M; ++j) {
                    float4 mv = *(const float4*)&sh_mem[j][k];
                    aS0[j] += mv.x * w00 + mv.y * w01 + mv.z * w02 + mv.w * w03;
                    aS1[j] += mv.x * w10 + mv.y * w11 + mv.z * w12 + mv.w * w13;
                    aC0[j] += mv.x * u00 + mv.y * u01 + mv.z * u02 + mv.w * u03;
                    aC1[j] += mv.x * u10 + mv.y * u11 + mv.z * u12 + mv.w * u13;
                }
            }
        }
        // slice 0 writes its partials (exclusive owner of its column pair)
        if (actB && s == 0) {
#pragma unroll
            for (int j = 0; j < M; ++j) {
                *(float2*)&sh_sim[j][c0]  = make_float2(aS0[j], aS1[j]);
                *(float2*)&sh_cand[j][c0] = make_float2(aC0[j], aC1[j]);
            }
        }
        __syncthreads();   // (2)
        if (actB && s != 0) {
#pragma unroll
            for (int j = 0; j < M; ++j) {
                atomicAdd(&sh_sim[j][c0],      aS0[j]);
                atomicAdd(&sh_sim[j][c0 + 1],  aS1[j]);
                atomicAdd(&sh_cand[j][c0],     aC0[j]);
                atomicAdd(&sh_cand[j][c0 + 1], aC1[j]);
            }
        }
        __syncthreads();   // (3)

        // ---- sim finish: relu(.)*Ws2, reduce over columns (lower waves) ----
        if (lower) {
            float usg[M];
#pragma unroll
            for (int j = 0; j < M; j += 4) {
                float4 u4 = *(const float4*)&sh_usage[j];
                usg[j] = u4.x; usg[j+1] = u4.y; usg[j+2] = u4.z; usg[j+3] = u4.w;
            }
#pragma unroll
            for (int j = 0; j < M; ++j) {
                float v = 0.f;
                if (actA) {
                    float pre = sh_sim[j][cA] + hb1reg + usg[j] * w900c;
                    v = fmaxf(pre, 0.0f) * ws2c;
                }
                for (int off = 32; off; off >>= 1) v += __shfl_xor(v, off, 64);
                if (lane == 0) sh_simpart[wave][j] = v;
            }
        }
        __syncthreads();   // (4)

        // ---- Phase C: decision (wave 0) ----
        if (wave == 0) {
            const bool act = lane < M;
            float simj = -INFINITY, usg = 0.0f;
            if (act) {
                float sv = sh_simpart[0][lane];
                sv += sh_simpart[1][lane];
                sv += sh_simpart[2][lane];
                sv += sh_simpart[3][lane];
                sv += sh_simpart[4][lane];
                simj = sv + bs2v;
                usg = sh_usage[lane];
            }
            float es = sh_entpart[0] + sh_entpart[1] + sh_entpart[2]
                     + sh_entpart[3] + sh_entpart[4] + be2v;
            const float entp = (1.0f / (1.0f + expf(-es))) * msk[tb];

            const float coref = (act && usg > 0.0f) ? 1.0f : 0.0f;
            float comb = act ? ((usg > 0.0f) ? simj : -10000.0f) : -INFINITY;
            float mx = comb;
            for (int off = 32; off; off >>= 1) mx = fmaxf(mx, __shfl_xor(mx, off, 64));
            mx = fmaxf(mx, 0.0f);
            float e = act ? expf(comb - mx) : 0.0f;
            const float eM = expf(0.0f - mx);
            float den = e;
            for (int off = 32; off; off >>= 1) den += __shfl_xor(den, off, 64);
            den += eM;
            const float prob  = e / den;
            const float probM = eM / den;
            float masked = prob * coref;
            float msum = masked;
            for (int off = 32; off; off >>= 1) msum += __shfl_xor(msum, off, 64);
            msum += probM;
            const float dn = msum + 1e-8f;
            const float normj = masked / dn;
            const float normM = probM / dn;
            const float indv = act ? (entp * normj) : 0.0f;
            const float ow_base = entp * normM;

            // nsim = softmax(sim)
            float nmx = simj;
            for (int off = 32; off; off >>= 1) nmx = fmaxf(nmx, __shfl_xor(nmx, off, 64));
            float ne = act ? expf(simj - nmx) : 0.0f;
            float ns = ne;
            for (int off = 32; off; off >>= 1) ns += __shfl_xor(ns, off, 64);
            const float nsim = ne / ns;

            float ows = act ? (((usg == 0.0f) ? nsim * 100000.0f : 0.0f) + (1.0f - usg))
                            : -INFINITY;
            float mv = ows;
            for (int off = 32; off; off >>= 1) mv = fmaxf(mv, __shfl_xor(mv, off, 64));

            float key = 0.0f;
            if (act && ows == mv) key = jax_noise((unsigned)(tb * M + lane));
            float bv = act ? key : -1.0f;
            int bi = act ? lane : 1023;
            for (int off = 32; off; off >>= 1) {
                float ov = __shfl_xor(bv, off, 64);
                int oi = __shfl_xor(bi, off, 64);
                if (ov > bv || (ov == bv && oi < bi)) { bv = ov; bi = oi; }
            }
            const float ow = (act && lane == bi) ? ow_base : 0.0f;
            const float nu = fminf(1.0f, (ow + indv) + 0.98f * usg);

            if (act) {
                sh_ow[lane] = ow;
                sh_indv[lane] = indv;
                sh_usage[lane] = nu;
                const int base = tb * M + lane;
                out[65536 + base]   = nu;                                   // usage_seq
                out[1376256 + base] = indv * (1.0f - 1e-8f) + 1e-8f;        // coref
                out[2686976 + base] = ow * (1.0f - 1e-8f) + 1e-8f;          // overwrite
            }
            if (lane == 0) out[tb] = entp * (1.0f - 1e-8f) + 1e-8f;          // ent
        }
        __syncthreads();   // (5)

        // ---- Phase D: memory update (upper half; cand = tanh(sum + hwu)) ----
        if (!lower && actA) {
            const float hc = sh_h[cA];
#pragma unroll
            for (int j = 0; j < M; ++j) {
                const float owj = sh_ow[j];
                const float inj = sh_indv[j];
                const float cd  = tanhf(sh_cand[j][cA] + hwureg);
                const float mo  = sh_mem[j][cA];
                sh_mem[j][cA] = owj * hc + (1.0f - owj - inj) * mo + inj * cd;
            }
        }
        __syncthreads();   // (6)
    }
}

extern "C" void kernel_launch(void* const* d_in, const int* in_sizes, int n_in,
                              void* d_out, int out_size, void* d_ws, size_t ws_size,
                              hipStream_t stream) {
    (void)in_sizes; (void)n_in; (void)d_ws; (void)ws_size; (void)out_size;
    const float* hs  = (const float*)d_in[0];
    const float* msk = (const float*)d_in[1];
    const float* We1 = (const float*)d_in[2];
    const float* be1 = (const float*)d_in[3];
    const float* We2 = (const float*)d_in[4];
    const float* be2 = (const float*)d_in[5];
    const float* Ws1 = (const float*)d_in[6];
    const float* bs1 = (const float*)d_in[7];
    const float* Ws2 = (const float*)d_in[8];
    const float* bs2 = (const float*)d_in[9];
    const float* Wu  = (const float*)d_in[10];
    const float* bu  = (const float*)d_in[11];
    float* out = (float*)d_out;

    hipLaunchKernelGGL(wm_kernel, dim3(BATCH), dim3(640), 0, stream,
                       hs, msk, We1, be1, We2, be2, Ws1, bs1, Ws2, bs2, Wu, bu, out);
}

// Round 3
// 50531.610 us; speedup vs baseline: 1.8818x; 1.8472x over previous
//
#include <hip/hip_runtime.h>
#include <math.h>

#define T_STEPS 512
#define BATCH   128
#define HDIM    300
#define M       20

// ---------------- JAX threefry2x32 noise replication ----------------
__device__ __forceinline__ unsigned rotl32(unsigned v, int r) {
    return (v << r) | (v >> (32 - r));
}

__device__ float jax_noise(unsigned i) {
#pragma clang fp contract(off)
    unsigned x0 = 0u;
    unsigned x1 = i;
    const unsigned ks0 = 0u, ks1 = 42u, ks2 = 0u ^ 42u ^ 0x1BD11BDAu;
    x0 += ks0; x1 += ks1;
    x0 += x1; x1 = rotl32(x1, 13); x1 ^= x0;
    x0 += x1; x1 = rotl32(x1, 15); x1 ^= x0;
    x0 += x1; x1 = rotl32(x1, 26); x1 ^= x0;
    x0 += x1; x1 = rotl32(x1, 6);  x1 ^= x0;
    x0 += ks1; x1 += ks2 + 1u;
    x0 += x1; x1 = rotl32(x1, 17); x1 ^= x0;
    x0 += x1; x1 = rotl32(x1, 29); x1 ^= x0;
    x0 += x1; x1 = rotl32(x1, 16); x1 ^= x0;
    x0 += x1; x1 = rotl32(x1, 24); x1 ^= x0;
    x0 += ks2; x1 += ks0 + 2u;
    x0 += x1; x1 = rotl32(x1, 13); x1 ^= x0;
    x0 += x1; x1 = rotl32(x1, 15); x1 ^= x0;
    x0 += x1; x1 = rotl32(x1, 26); x1 ^= x0;
    x0 += x1; x1 = rotl32(x1, 6);  x1 ^= x0;
    x0 += ks0; x1 += ks1 + 3u;
    x0 += x1; x1 = rotl32(x1, 17); x1 ^= x0;
    x0 += x1; x1 = rotl32(x1, 29); x1 ^= x0;
    x0 += x1; x1 = rotl32(x1, 16); x1 ^= x0;
    x0 += x1; x1 = rotl32(x1, 24); x1 ^= x0;
    x0 += ks1; x1 += ks2 + 4u;
    x0 += x1; x1 = rotl32(x1, 13); x1 ^= x0;
    x0 += x1; x1 = rotl32(x1, 15); x1 ^= x0;
    x0 += x1; x1 = rotl32(x1, 26); x1 ^= x0;
    x0 += x1; x1 = rotl32(x1, 6);  x1 ^= x0;
    x0 += ks2; x1 += ks0 + 5u;

    const unsigned bits = x0 ^ x1;
    const unsigned fb = (bits >> 9) | 0x3f800000u;
    float f = __uint_as_float(fb) - 1.0f;
    const float span = 1.0f - 0.01f;
    float v = f * span;
    v = v + 0.01f;
    return fmaxf(0.01f, v);
}

// 20-way static expansion: guarantees compile-time-constant indexing so the
// 80 accumulators are promotable scalars (R1/R2 failure: array allocas never
// promoted by SROA -> 15.5 GB scratch traffic, VGPR stuck at 84).
#define FOR20(X) X(0) X(1) X(2) X(3) X(4) X(5) X(6) X(7) X(8) X(9) \
                 X(10) X(11) X(12) X(13) X(14) X(15) X(16) X(17) X(18) X(19)

// ---------------- main persistent per-batch kernel ----------------
// grid = 128 blocks (one per batch element), 640 threads = 10 waves.
// LDS padded >80KB: forces 1 block/CU occupancy target so the register
// budget is the 3-waves/SIMD cap (~170), not the 2-block budget (~102).
// (128 blocks on 256 CUs -> never 2 blocks/CU anyway; pad costs nothing.)
// Phase A (GEMVs): threads 0-319 -> hb1/ent columns; 320-639 -> hwu columns.
// Phase B (big GEMMs): thread = (k-slice s = tid/160, column-pair p = tid%160).
//   Each thread computes BOTH sim and cand partials for 2 columns over 1/4 of K,
//   so each sh_mem broadcast read feeds 16 FMAs -> ~4x fewer LDS instrs vs R0.
__global__ void __launch_bounds__(640, 3)
wm_kernel(const float* __restrict__ hs,   // (T,B,H)
          const float* __restrict__ msk,  // (T,B)
          const float* __restrict__ We1,  // (300,300)
          const float* __restrict__ be1,  // (300)
          const float* __restrict__ We2,  // (300,1)
          const float* __restrict__ be2,  // (1)
          const float* __restrict__ Ws1,  // (901,300)
          const float* __restrict__ bs1,  // (300)
          const float* __restrict__ Ws2,  // (300,1)
          const float* __restrict__ bs2,  // (1)
          const float* __restrict__ Wu,   // (600,300)
          const float* __restrict__ bu,   // (300)
          float* __restrict__ out)
{
    __shared__ __align__(16) float sh_mem[M][HDIM];
    __shared__ __align__(16) float sh_h[HDIM + 2080];   // +8320B pad -> LDS >80KB (occupancy target = 1 block/CU)
    __shared__ __align__(16) float sh_sim[M][HDIM];     // sim slice-reduction buffer
    __shared__ __align__(16) float sh_cand[M][HDIM];    // cand slice-reduction buffer
    __shared__ __align__(16) float sh_usage[M];
    __shared__ float sh_simpart[5][M];
    __shared__ float sh_entpart[5];
    __shared__ float sh_ow[M];
    __shared__ float sh_indv[M];

    const int b    = blockIdx.x;
    const int tid  = threadIdx.x;
    const int wave = tid >> 6;   // 0..9
    const int lane = tid & 63;

    // ---- Phase A / sim-finish / Phase D mapping ----
    const bool lower = tid < 320;
    const int cA     = lower ? tid : (tid - 320);
    const bool actA  = cA < HDIM;

    // ---- Phase B mapping: 4 k-slices x 150 column-pairs ----
    const int  s    = tid / 160;          // k-slice 0..3
    const int  p    = tid % 160;          // column-pair
    const bool actB = p < 150;
    const int  c0   = 2 * p;              // columns c0, c0+1
    const int  kbeg = s * 76;
    const int  kend = (s == 3) ? 300 : (kbeg + 76);   // slices: 76,76,76,72

    // ---- init state ----
    for (int idx = tid; idx < M * HDIM; idx += 640) ((float*)sh_mem)[idx] = 0.0f;
    if (tid < M) sh_usage[tid] = 0.0f;

    const float be2v = be2[0];
    const float bs2v = bs2[0];
    // step-invariant per-column scalars
    float bs1c = 0.f, be1c = 0.f, we2c = 0.f, ws2c = 0.f, w900c = 0.f, buc = 0.f;
    if (actA) {
        if (lower) {
            bs1c = bs1[cA]; be1c = be1[cA]; we2c = We2[cA];
            ws2c = Ws2[cA]; w900c = Ws1[900 * 300 + cA];
        } else {
            buc = bu[cA];
        }
    }
    __syncthreads();

    for (int t = 0; t < T_STEPS; ++t) {
        const int tb = t * BATCH + b;

        // ---- load h (upper half) ----
        if (!lower && actA) sh_h[cA] = hs[(size_t)tb * HDIM + cA];
        __syncthreads();   // (1) h ready; prev step fully done

        // ---- Phase A: h-GEMVs (hb1, hwu in registers; ent partials) ----
        float hb1reg = 0.f, hwureg = 0.f;
        {
            float a1 = 0.f, ae = 0.f, au = 0.f;
            if (actA) {
                if (lower) {
                    const float* pB = Ws1 + 90000 + cA;   // rows 300..599
                    const float* pE = We1 + cA;
                    for (int k = 0; k < HDIM; k += 4) {
                        float4 h4 = *(const float4*)&sh_h[k];
                        const float* q  = pB + k * 300;
                        const float* qe = pE + k * 300;
                        a1 += h4.x * q[0] + h4.y * q[300] + h4.z * q[600] + h4.w * q[900];
                        ae += h4.x * qe[0] + h4.y * qe[300] + h4.z * qe[600] + h4.w * qe[900];
                    }
                } else {
                    const float* pU = Wu + cA;            // rows 0..299
                    for (int k = 0; k < HDIM; k += 4) {
                        float4 h4 = *(const float4*)&sh_h[k];
                        const float* q = pU + k * 300;
                        au += h4.x * q[0] + h4.y * q[300] + h4.z * q[600] + h4.w * q[900];
                    }
                }
            }
            if (lower) {
                float er = actA ? (fmaxf(ae + be1c, 0.0f) * we2c) : 0.0f;
                for (int off = 32; off; off >>= 1) er += __shfl_xor(er, off, 64);
                if (lane == 0) sh_entpart[wave] = er;
                hb1reg = a1 + bs1c;
            } else {
                hwureg = au + buc;
            }
        }

        // ---- Phase B: fused sim+cand K-slice loop, 2 columns per thread ----
        // 80 NAMED scalar accumulators (not arrays -> guaranteed registers).
#define DECL_ACC(j) float aS0_##j = 0.f, aS1_##j = 0.f, aC0_##j = 0.f, aC1_##j = 0.f;
        FOR20(DECL_ACC)
#undef DECL_ACC

        if (actB) {
#pragma unroll 1
            for (int k = kbeg; k < kend; k += 4) {
                float4 h4 = *(const float4*)&sh_h[k];
                const float2* qa = (const float2*)(Ws1 + c0 + k * 300);            // rows 0..299   (mem)
                const float2* qc = (const float2*)(Ws1 + 180000 + c0 + k * 300);   // rows 600..899 (h*mem)
                const float2* qu = (const float2*)(Wu + 90000 + c0 + k * 300);     // rows 300..599 (mem)
                float2 a0 = qa[0], a1v = qa[150], a2 = qa[300], a3 = qa[450];
                float2 c0v = qc[0], c1v = qc[150], c2v = qc[300], c3v = qc[450];
                float2 u0v = qu[0], u1v = qu[150], u2v = qu[300], u3v = qu[450];
                float w00 = fmaf(h4.x, c0v.x, a0.x);
                float w01 = fmaf(h4.y, c1v.x, a1v.x);
                float w02 = fmaf(h4.z, c2v.x, a2.x);
                float w03 = fmaf(h4.w, c3v.x, a3.x);
                float w10 = fmaf(h4.x, c0v.y, a0.y);
                float w11 = fmaf(h4.y, c1v.y, a1v.y);
                float w12 = fmaf(h4.z, c2v.y, a2.y);
                float w13 = fmaf(h4.w, c3v.y, a3.y);
                float u00 = u0v.x, u01 = u1v.x, u02 = u2v.x, u03 = u3v.x;
                float u10 = u0v.y, u11 = u1v.y, u12 = u2v.y, u13 = u3v.y;
#define ACC_J(j) { \
                float4 mv = *(const float4*)&sh_mem[j][k]; \
                aS0_##j += mv.x * w00 + mv.y * w01 + mv.z * w02 + mv.w * w03; \
                aS1_##j += mv.x * w10 + mv.y * w11 + mv.z * w12 + mv.w * w13; \
                aC0_##j += mv.x * u00 + mv.y * u01 + mv.z * u02 + mv.w * u03; \
                aC1_##j += mv.x * u10 + mv.y * u11 + mv.z * u12 + mv.w * u13; }
                FOR20(ACC_J)
#undef ACC_J
            }
        }
        // slice 0 writes its partials (exclusive owner of its column pair)
        if (actB && s == 0) {
#define WB_S0(j) { \
            *(float2*)&sh_sim[j][c0]  = make_float2(aS0_##j, aS1_##j); \
            *(float2*)&sh_cand[j][c0] = make_float2(aC0_##j, aC1_##j); }
            FOR20(WB_S0)
#undef WB_S0
        }
        __syncthreads();   // (2)
        if (actB && s != 0) {
#define WB_AT(j) { \
            atomicAdd(&sh_sim[j][c0],      aS0_##j); \
            atomicAdd(&sh_sim[j][c0 + 1],  aS1_##j); \
            atomicAdd(&sh_cand[j][c0],     aC0_##j); \
            atomicAdd(&sh_cand[j][c0 + 1], aC1_##j); }
            FOR20(WB_AT)
#undef WB_AT
        }
        __syncthreads();   // (3)

        // ---- sim finish: relu(.)*Ws2, reduce over columns (lower waves) ----
        if (lower) {
#pragma unroll
            for (int j = 0; j < M; ++j) {
                float v = 0.f;
                if (actA) {
                    float pre = sh_sim[j][cA] + hb1reg + sh_usage[j] * w900c;
                    v = fmaxf(pre, 0.0f) * ws2c;
                }
                for (int off = 32; off; off >>= 1) v += __shfl_xor(v, off, 64);
                if (lane == 0) sh_simpart[wave][j] = v;
            }
        }
        __syncthreads();   // (4)

        // ---- Phase C: decision (wave 0) ----
        if (wave == 0) {
            const bool act = lane < M;
            float simj = -INFINITY, usg = 0.0f;
            if (act) {
                float sv = sh_simpart[0][lane];
                sv += sh_simpart[1][lane];
                sv += sh_simpart[2][lane];
                sv += sh_simpart[3][lane];
                sv += sh_simpart[4][lane];
                simj = sv + bs2v;
                usg = sh_usage[lane];
            }
            float es = sh_entpart[0] + sh_entpart[1] + sh_entpart[2]
                     + sh_entpart[3] + sh_entpart[4] + be2v;
            const float entp = (1.0f / (1.0f + expf(-es))) * msk[tb];

            const float coref = (act && usg > 0.0f) ? 1.0f : 0.0f;
            float comb = act ? ((usg > 0.0f) ? simj : -10000.0f) : -INFINITY;
            float mx = comb;
            for (int off = 32; off; off >>= 1) mx = fmaxf(mx, __shfl_xor(mx, off, 64));
            mx = fmaxf(mx, 0.0f);
            float e = act ? expf(comb - mx) : 0.0f;
            const float eM = expf(0.0f - mx);
            float den = e;
            for (int off = 32; off; off >>= 1) den += __shfl_xor(den, off, 64);
            den += eM;
            const float prob  = e / den;
            const float probM = eM / den;
            float masked = prob * coref;
            float msum = masked;
            for (int off = 32; off; off >>= 1) msum += __shfl_xor(msum, off, 64);
            msum += probM;
            const float dn = msum + 1e-8f;
            const float normj = masked / dn;
            const float normM = probM / dn;
            const float indv = act ? (entp * normj) : 0.0f;
            const float ow_base = entp * normM;

            // nsim = softmax(sim)
            float nmx = simj;
            for (int off = 32; off; off >>= 1) nmx = fmaxf(nmx, __shfl_xor(nmx, off, 64));
            float ne = act ? expf(simj - nmx) : 0.0f;
            float ns = ne;
            for (int off = 32; off; off >>= 1) ns += __shfl_xor(ns, off, 64);
            const float nsim = ne / ns;

            float ows = act ? (((usg == 0.0f) ? nsim * 100000.0f : 0.0f) + (1.0f - usg))
                            : -INFINITY;
            float mv = ows;
            for (int off = 32; off; off >>= 1) mv = fmaxf(mv, __shfl_xor(mv, off, 64));

            float key = 0.0f;
            if (act && ows == mv) key = jax_noise((unsigned)(tb * M + lane));
            float bv = act ? key : -1.0f;
            int bi = act ? lane : 1023;
            for (int off = 32; off; off >>= 1) {
                float ov = __shfl_xor(bv, off, 64);
                int oi = __shfl_xor(bi, off, 64);
                if (ov > bv || (ov == bv && oi < bi)) { bv = ov; bi = oi; }
            }
            const float ow = (act && lane == bi) ? ow_base : 0.0f;
            const float nu = fminf(1.0f, (ow + indv) + 0.98f * usg);

            if (act) {
                sh_ow[lane] = ow;
                sh_indv[lane] = indv;
                sh_usage[lane] = nu;
                const int base = tb * M + lane;
                out[65536 + base]   = nu;                                   // usage_seq
                out[1376256 + base] = indv * (1.0f - 1e-8f) + 1e-8f;        // coref
                out[2686976 + base] = ow * (1.0f - 1e-8f) + 1e-8f;          // overwrite
            }
            if (lane == 0) out[tb] = entp * (1.0f - 1e-8f) + 1e-8f;          // ent
        }
        __syncthreads();   // (5)

        // ---- Phase D: memory update (upper half; cand = tanh(sum + hwu)) ----
        if (!lower && actA) {
            const float hc = sh_h[cA];
#pragma unroll
            for (int j = 0; j < M; ++j) {
                const float owj = sh_ow[j];
                const float inj = sh_indv[j];
                const float cd  = tanhf(sh_cand[j][cA] + hwureg);
                const float mo  = sh_mem[j][cA];
                sh_mem[j][cA] = owj * hc + (1.0f - owj - inj) * mo + inj * cd;
            }
        }
        __syncthreads();   // (6)
    }
}

extern "C" void kernel_launch(void* const* d_in, const int* in_sizes, int n_in,
                              void* d_out, int out_size, void* d_ws, size_t ws_size,
                              hipStream_t stream) {
    (void)in_sizes; (void)n_in; (void)d_ws; (void)ws_size; (void)out_size;
    const float* hs  = (const float*)d_in[0];
    const float* msk = (const float*)d_in[1];
    const float* We1 = (const float*)d_in[2];
    const float* be1 = (const float*)d_in[3];
    const float* We2 = (const float*)d_in[4];
    const float* be2 = (const float*)d_in[5];
    const float* Ws1 = (const float*)d_in[6];
    const float* bs1 = (const float*)d_in[7];
    const float* Ws2 = (const float*)d_in[8];
    const float* bs2 = (const float*)d_in[9];
    const float* Wu  = (const float*)d_in[10];
    const float* bu  = (const float*)d_in[11];
    float* out = (float*)d_out;

    hipLaunchKernelGGL(wm_kernel, dim3(BATCH), dim3(640), 0, stream,
                       hs, msk, We1, be1, We2, be2, Ws1, bs1, Ws2, bs2, Wu, bu, out);
}

// Round 4
// 46524.841 us; speedup vs baseline: 2.0439x; 1.0861x over previous
//
#include <hip/hip_runtime.h>
#include <math.h>

#define T_STEPS 512
#define BATCH   128
#define HDIM    300
#define M       20

// ---------------- JAX threefry2x32 noise replication ----------------
__device__ __forceinline__ unsigned rotl32(unsigned v, int r) {
    return (v << r) | (v >> (32 - r));
}

__device__ float jax_noise(unsigned i) {
#pragma clang fp contract(off)
    unsigned x0 = 0u;
    unsigned x1 = i;
    const unsigned ks0 = 0u, ks1 = 42u, ks2 = 0u ^ 42u ^ 0x1BD11BDAu;
    x0 += ks0; x1 += ks1;
    x0 += x1; x1 = rotl32(x1, 13); x1 ^= x0;
    x0 += x1; x1 = rotl32(x1, 15); x1 ^= x0;
    x0 += x1; x1 = rotl32(x1, 26); x1 ^= x0;
    x0 += x1; x1 = rotl32(x1, 6);  x1 ^= x0;
    x0 += ks1; x1 += ks2 + 1u;
    x0 += x1; x1 = rotl32(x1, 17); x1 ^= x0;
    x0 += x1; x1 = rotl32(x1, 29); x1 ^= x0;
    x0 += x1; x1 = rotl32(x1, 16); x1 ^= x0;
    x0 += x1; x1 = rotl32(x1, 24); x1 ^= x0;
    x0 += ks2; x1 += ks0 + 2u;
    x0 += x1; x1 = rotl32(x1, 13); x1 ^= x0;
    x0 += x1; x1 = rotl32(x1, 15); x1 ^= x0;
    x0 += x1; x1 = rotl32(x1, 26); x1 ^= x0;
    x0 += x1; x1 = rotl32(x1, 6);  x1 ^= x0;
    x0 += ks0; x1 += ks1 + 3u;
    x0 += x1; x1 = rotl32(x1, 17); x1 ^= x0;
    x0 += x1; x1 = rotl32(x1, 29); x1 ^= x0;
    x0 += x1; x1 = rotl32(x1, 16); x1 ^= x0;
    x0 += x1; x1 = rotl32(x1, 24); x1 ^= x0;
    x0 += ks1; x1 += ks2 + 4u;
    x0 += x1; x1 = rotl32(x1, 13); x1 ^= x0;
    x0 += x1; x1 = rotl32(x1, 15); x1 ^= x0;
    x0 += x1; x1 = rotl32(x1, 26); x1 ^= x0;
    x0 += x1; x1 = rotl32(x1, 6);  x1 ^= x0;
    x0 += ks2; x1 += ks0 + 5u;

    const unsigned bits = x0 ^ x1;
    const unsigned fb = (bits >> 9) | 0x3f800000u;
    float f = __uint_as_float(fb) - 1.0f;
    const float span = 1.0f - 0.01f;
    float v = f * span;
    v = v + 0.01f;
    return fmaxf(0.01f, v);
}

#define FOR10(X) X(0) X(1) X(2) X(3) X(4) X(5) X(6) X(7) X(8) X(9)

// ---------------- main persistent per-batch kernel ----------------
// grid = 128 blocks (one per batch element), 640 threads = 10 waves.
//
// Phase B mapping (R4): 600 threads = 300 columns x 2 j-groups (j 0-9 / 10-19).
// Each thread owns ONE column, TEN j's, BOTH paths (sim+cand), FULL K:
//   - 20 named scalar accumulators -> guaranteed arch VGPRs (no AGPR overflow,
//     no scratch; R1-R3 lesson).
//   - each sh_mem broadcast read feeds 8 FMAs (2x R0's 4).
//   - every (j,c) output written by exactly ONE thread -> no LDS atomics,
//     no cross-thread reduction, no extra barrier (R3's serializers removed).
//   - no unroll pragma: compiler free to software-pipeline the k-loop.
__global__ void __launch_bounds__(640, 3)
wm_kernel(const float* __restrict__ hs,   // (T,B,H)
          const float* __restrict__ msk,  // (T,B)
          const float* __restrict__ We1,  // (300,300)
          const float* __restrict__ be1,  // (300)
          const float* __restrict__ We2,  // (300,1)
          const float* __restrict__ be2,  // (1)
          const float* __restrict__ Ws1,  // (901,300)
          const float* __restrict__ bs1,  // (300)
          const float* __restrict__ Ws2,  // (300,1)
          const float* __restrict__ bs2,  // (1)
          const float* __restrict__ Wu,   // (600,300)
          const float* __restrict__ bu,   // (300)
          float* __restrict__ out)
{
    __shared__ __align__(16) float sh_mem[M][HDIM];
    __shared__ __align__(16) float sh_h[HDIM + 2080];   // pad -> LDS >80KB (1 block/CU reg budget)
    __shared__ __align__(16) float sh_sim[M][HDIM];     // mem-dependent sim partial per (j,c)
    __shared__ __align__(16) float sh_cand[M][HDIM];    // mem-dependent cand partial per (j,c)
    __shared__ __align__(16) float sh_usage[M];
    __shared__ float sh_simpart[5][M];
    __shared__ float sh_entpart[5];
    __shared__ float sh_ow[M];
    __shared__ float sh_indv[M];

    const int b    = blockIdx.x;
    const int tid  = threadIdx.x;
    const int wave = tid >> 6;   // 0..9
    const int lane = tid & 63;

    // ---- Phase A / sim-finish / Phase D mapping ----
    const bool lower = tid < 320;
    const int cA     = lower ? tid : (tid - 320);
    const bool actA  = cA < HDIM;

    // ---- Phase B mapping: 300 columns x 2 j-groups ----
    const bool actB = tid < 600;
    const int  cB   = (tid < 300) ? tid : (tid - 300);
    const int  jb   = (tid < 300) ? 0 : 10;   // j-base (uniform per thread; no branch divergence)

    // ---- init state ----
    for (int idx = tid; idx < M * HDIM; idx += 640) ((float*)sh_mem)[idx] = 0.0f;
    if (tid < M) sh_usage[tid] = 0.0f;

    const float be2v = be2[0];
    const float bs2v = bs2[0];
    // step-invariant per-column scalars
    float bs1c = 0.f, be1c = 0.f, we2c = 0.f, ws2c = 0.f, w900c = 0.f, buc = 0.f;
    if (actA) {
        if (lower) {
            bs1c = bs1[cA]; be1c = be1[cA]; we2c = We2[cA];
            ws2c = Ws2[cA]; w900c = Ws1[900 * 300 + cA];
        } else {
            buc = bu[cA];
        }
    }
    __syncthreads();

    for (int t = 0; t < T_STEPS; ++t) {
        const int tb = t * BATCH + b;

        // ---- load h (upper half) ----
        if (!lower && actA) sh_h[cA] = hs[(size_t)tb * HDIM + cA];
        __syncthreads();   // (1) h ready; prev step fully done

        // ---- Phase A: h-GEMVs (hb1, hwu in registers; ent partials) ----
        float hb1reg = 0.f, hwureg = 0.f;
        {
            float a1 = 0.f, ae = 0.f, au = 0.f;
            if (actA) {
                if (lower) {
                    const float* pB = Ws1 + 90000 + cA;   // rows 300..599
                    const float* pE = We1 + cA;
                    for (int k = 0; k < HDIM; k += 4) {
                        float4 h4 = *(const float4*)&sh_h[k];
                        const float* q  = pB + k * 300;
                        const float* qe = pE + k * 300;
                        a1 += h4.x * q[0] + h4.y * q[300] + h4.z * q[600] + h4.w * q[900];
                        ae += h4.x * qe[0] + h4.y * qe[300] + h4.z * qe[600] + h4.w * qe[900];
                    }
                } else {
                    const float* pU = Wu + cA;            // rows 0..299
                    for (int k = 0; k < HDIM; k += 4) {
                        float4 h4 = *(const float4*)&sh_h[k];
                        const float* q = pU + k * 300;
                        au += h4.x * q[0] + h4.y * q[300] + h4.z * q[600] + h4.w * q[900];
                    }
                }
            }
            if (lower) {
                float er = actA ? (fmaxf(ae + be1c, 0.0f) * we2c) : 0.0f;
                for (int off = 32; off; off >>= 1) er += __shfl_xor(er, off, 64);
                if (lane == 0) sh_entpart[wave] = er;
                hb1reg = a1 + bs1c;
            } else {
                hwureg = au + buc;
            }
        }

        // ---- Phase B: fused sim+cand, 1 column x 10 j's x full K per thread ----
#define DECL_ACC(jj) float aS_##jj = 0.f, aC_##jj = 0.f;
        FOR10(DECL_ACC)
#undef DECL_ACC

        if (actB) {
            const float* qa = Ws1 + cB;            // rows 0..299   (mem)
            const float* qc = Ws1 + 180000 + cB;   // rows 600..899 (h*mem)
            const float* qu = Wu + 90000 + cB;     // rows 300..599 (mem)
            for (int k = 0; k < HDIM; k += 4) {
                float4 h4 = *(const float4*)&sh_h[k];
                const float* ra = qa + k * 300;
                const float* rc = qc + k * 300;
                const float* ru = qu + k * 300;
                float w0 = fmaf(h4.x, rc[0],   ra[0]);
                float w1 = fmaf(h4.y, rc[300], ra[300]);
                float w2 = fmaf(h4.z, rc[600], ra[600]);
                float w3 = fmaf(h4.w, rc[900], ra[900]);
                float u0 = ru[0], u1 = ru[300], u2 = ru[600], u3 = ru[900];
#define ACC_J(jj) { \
                float4 mv = *(const float4*)&sh_mem[jb + jj][k]; \
                aS_##jj += mv.x * w0 + mv.y * w1 + mv.z * w2 + mv.w * w3; \
                aC_##jj += mv.x * u0 + mv.y * u1 + mv.z * u2 + mv.w * u3; }
                FOR10(ACC_J)
#undef ACC_J
            }
#define WB(jj) { sh_sim[jb + jj][cB] = aS_##jj; sh_cand[jb + jj][cB] = aC_##jj; }
            FOR10(WB)
#undef WB
        }
        __syncthreads();   // (2) sim/cand partials complete

        // ---- sim finish: relu(.)*Ws2, reduce over columns (lower waves) ----
        if (lower) {
#pragma unroll
            for (int j = 0; j < M; ++j) {
                float v = 0.f;
                if (actA) {
                    float pre = sh_sim[j][cA] + hb1reg + sh_usage[j] * w900c;
                    v = fmaxf(pre, 0.0f) * ws2c;
                }
                for (int off = 32; off; off >>= 1) v += __shfl_xor(v, off, 64);
                if (lane == 0) sh_simpart[wave][j] = v;
            }
        }
        __syncthreads();   // (3)

        // ---- Phase C: decision (wave 0) ----
        if (wave == 0) {
            const bool act = lane < M;
            float simj = -INFINITY, usg = 0.0f;
            if (act) {
                float sv = sh_simpart[0][lane];
                sv += sh_simpart[1][lane];
                sv += sh_simpart[2][lane];
                sv += sh_simpart[3][lane];
                sv += sh_simpart[4][lane];
                simj = sv + bs2v;
                usg = sh_usage[lane];
            }
            float es = sh_entpart[0] + sh_entpart[1] + sh_entpart[2]
                     + sh_entpart[3] + sh_entpart[4] + be2v;
            const float entp = (1.0f / (1.0f + expf(-es))) * msk[tb];

            const float coref = (act && usg > 0.0f) ? 1.0f : 0.0f;
            float comb = act ? ((usg > 0.0f) ? simj : -10000.0f) : -INFINITY;
            float mx = comb;
            for (int off = 32; off; off >>= 1) mx = fmaxf(mx, __shfl_xor(mx, off, 64));
            mx = fmaxf(mx, 0.0f);
            float e = act ? expf(comb - mx) : 0.0f;
            const float eM = expf(0.0f - mx);
            float den = e;
            for (int off = 32; off; off >>= 1) den += __shfl_xor(den, off, 64);
            den += eM;
            const float prob  = e / den;
            const float probM = eM / den;
            float masked = prob * coref;
            float msum = masked;
            for (int off = 32; off; off >>= 1) msum += __shfl_xor(msum, off, 64);
            msum += probM;
            const float dn = msum + 1e-8f;
            const float normj = masked / dn;
            const float normM = probM / dn;
            const float indv = act ? (entp * normj) : 0.0f;
            const float ow_base = entp * normM;

            // nsim = softmax(sim)
            float nmx = simj;
            for (int off = 32; off; off >>= 1) nmx = fmaxf(nmx, __shfl_xor(nmx, off, 64));
            float ne = act ? expf(simj - nmx) : 0.0f;
            float ns = ne;
            for (int off = 32; off; off >>= 1) ns += __shfl_xor(ns, off, 64);
            const float nsim = ne / ns;

            float ows = act ? (((usg == 0.0f) ? nsim * 100000.0f : 0.0f) + (1.0f - usg))
                            : -INFINITY;
            float mv = ows;
            for (int off = 32; off; off >>= 1) mv = fmaxf(mv, __shfl_xor(mv, off, 64));

            float key = 0.0f;
            if (act && ows == mv) key = jax_noise((unsigned)(tb * M + lane));
            float bv = act ? key : -1.0f;
            int bi = act ? lane : 1023;
            for (int off = 32; off; off >>= 1) {
                float ov = __shfl_xor(bv, off, 64);
                int oi = __shfl_xor(bi, off, 64);
                if (ov > bv || (ov == bv && oi < bi)) { bv = ov; bi = oi; }
            }
            const float ow = (act && lane == bi) ? ow_base : 0.0f;
            const float nu = fminf(1.0f, (ow + indv) + 0.98f * usg);

            if (act) {
                sh_ow[lane] = ow;
                sh_indv[lane] = indv;
                sh_usage[lane] = nu;
                const int base = tb * M + lane;
                out[65536 + base]   = nu;                                   // usage_seq
                out[1376256 + base] = indv * (1.0f - 1e-8f) + 1e-8f;        // coref
                out[2686976 + base] = ow * (1.0f - 1e-8f) + 1e-8f;          // overwrite
            }
            if (lane == 0) out[tb] = entp * (1.0f - 1e-8f) + 1e-8f;          // ent
        }
        __syncthreads();   // (4)

        // ---- Phase D: memory update (upper half; cand = tanh(sum + hwu)) ----
        if (!lower && actA) {
            const float hc = sh_h[cA];
#pragma unroll
            for (int j = 0; j < M; ++j) {
                const float owj = sh_ow[j];
                const float inj = sh_indv[j];
                const float cd  = tanhf(sh_cand[j][cA] + hwureg);
                const float mo  = sh_mem[j][cA];
                sh_mem[j][cA] = owj * hc + (1.0f - owj - inj) * mo + inj * cd;
            }
        }
        __syncthreads();   // (5)
    }
}

extern "C" void kernel_launch(void* const* d_in, const int* in_sizes, int n_in,
                              void* d_out, int out_size, void* d_ws, size_t ws_size,
                              hipStream_t stream) {
    (void)in_sizes; (void)n_in; (void)d_ws; (void)ws_size; (void)out_size;
    const float* hs  = (const float*)d_in[0];
    const float* msk = (const float*)d_in[1];
    const float* We1 = (const float*)d_in[2];
    const float* be1 = (const float*)d_in[3];
    const float* We2 = (const float*)d_in[4];
    const float* be2 = (const float*)d_in[5];
    const float* Ws1 = (const float*)d_in[6];
    const float* bs1 = (const float*)d_in[7];
    const float* Ws2 = (const float*)d_in[8];
    const float* bs2 = (const float*)d_in[9];
    const float* Wu  = (const float*)d_in[10];
    const float* bu  = (const float*)d_in[11];
    float* out = (float*)d_out;

    hipLaunchKernelGGL(wm_kernel, dim3(BATCH), dim3(640), 0, stream,
                       hs, msk, We1, be1, We2, be2, Ws1, bs1, Ws2, bs2, Wu, bu, out);
}

// Round 5
// 43108.841 us; speedup vs baseline: 2.2058x; 1.0792x over previous
//
#include <hip/hip_runtime.h>
#include <math.h>

#define T_STEPS 512
#define BATCH   128
#define HDIM    300
#define M       20

// ---------------- JAX threefry2x32 noise replication ----------------
__device__ __forceinline__ unsigned rotl32(unsigned v, int r) {
    return (v << r) | (v >> (32 - r));
}

__device__ float jax_noise(unsigned i) {
#pragma clang fp contract(off)
    unsigned x0 = 0u;
    unsigned x1 = i;
    const unsigned ks0 = 0u, ks1 = 42u, ks2 = 0u ^ 42u ^ 0x1BD11BDAu;
    x0 += ks0; x1 += ks1;
    x0 += x1; x1 = rotl32(x1, 13); x1 ^= x0;
    x0 += x1; x1 = rotl32(x1, 15); x1 ^= x0;
    x0 += x1; x1 = rotl32(x1, 26); x1 ^= x0;
    x0 += x1; x1 = rotl32(x1, 6);  x1 ^= x0;
    x0 += ks1; x1 += ks2 + 1u;
    x0 += x1; x1 = rotl32(x1, 17); x1 ^= x0;
    x0 += x1; x1 = rotl32(x1, 29); x1 ^= x0;
    x0 += x1; x1 = rotl32(x1, 16); x1 ^= x0;
    x0 += x1; x1 = rotl32(x1, 24); x1 ^= x0;
    x0 += ks2; x1 += ks0 + 2u;
    x0 += x1; x1 = rotl32(x1, 13); x1 ^= x0;
    x0 += x1; x1 = rotl32(x1, 15); x1 ^= x0;
    x0 += x1; x1 = rotl32(x1, 26); x1 ^= x0;
    x0 += x1; x1 = rotl32(x1, 6);  x1 ^= x0;
    x0 += ks0; x1 += ks1 + 3u;
    x0 += x1; x1 = rotl32(x1, 17); x1 ^= x0;
    x0 += x1; x1 = rotl32(x1, 29); x1 ^= x0;
    x0 += x1; x1 = rotl32(x1, 16); x1 ^= x0;
    x0 += x1; x1 = rotl32(x1, 24); x1 ^= x0;
    x0 += ks1; x1 += ks2 + 4u;
    x0 += x1; x1 = rotl32(x1, 13); x1 ^= x0;
    x0 += x1; x1 = rotl32(x1, 15); x1 ^= x0;
    x0 += x1; x1 = rotl32(x1, 26); x1 ^= x0;
    x0 += x1; x1 = rotl32(x1, 6);  x1 ^= x0;
    x0 += ks2; x1 += ks0 + 5u;

    const unsigned bits = x0 ^ x1;
    const unsigned fb = (bits >> 9) | 0x3f800000u;
    float f = __uint_as_float(fb) - 1.0f;
    const float span = 1.0f - 0.01f;
    float v = f * span;
    v = v + 0.01f;
    return fmaxf(0.01f, v);
}

#define FOR5(X) X(0) X(1) X(2) X(3) X(4)

// ---------------- main persistent per-batch kernel ----------------
// grid = 128 blocks (one per batch element), 640 threads = 10 waves.
//
// Phase B mapping (R5): 600 threads = 4 j-groups (5 j's) x 150 column-pairs.
// Each thread: 2 adjacent columns x 5 j's x BOTH paths (20 named scalar accs):
//   - each sh_mem broadcast read feeds 16 FMAs (2x R4) -> 4500 LDS instr/CU/step
//   - weights loaded as float2 (adjacent cols), with EXPLICIT one-iteration
//     prefetch into rotation registers: the ~220cy L2 latency that R4's 2.5
//     waves/SIMD could not hide (R4: all pipes <45% busy => latency-bound)
//     is moved off the critical path.
//   - every (j,c) output written by exactly one thread -> no atomics.
__global__ void __launch_bounds__(640, 3)
wm_kernel(const float* __restrict__ hs,   // (T,B,H)
          const float* __restrict__ msk,  // (T,B)
          const float* __restrict__ We1,  // (300,300)
          const float* __restrict__ be1,  // (300)
          const float* __restrict__ We2,  // (300,1)
          const float* __restrict__ be2,  // (1)
          const float* __restrict__ Ws1,  // (901,300)
          const float* __restrict__ bs1,  // (300)
          const float* __restrict__ Ws2,  // (300,1)
          const float* __restrict__ bs2,  // (1)
          const float* __restrict__ Wu,   // (600,300)
          const float* __restrict__ bu,   // (300)
          float* __restrict__ out)
{
    __shared__ __align__(16) float sh_mem[M][HDIM];
    __shared__ __align__(16) float sh_h[HDIM + 2080];   // pad -> LDS >80KB (1 block/CU reg budget)
    __shared__ __align__(16) float sh_sim[M][HDIM];     // mem-dependent sim partial per (j,c)
    __shared__ __align__(16) float sh_cand[M][HDIM];    // mem-dependent cand partial per (j,c)
    __shared__ __align__(16) float sh_usage[M];
    __shared__ float sh_simpart[5][M];
    __shared__ float sh_entpart[5];
    __shared__ float sh_ow[M];
    __shared__ float sh_indv[M];

    const int b    = blockIdx.x;
    const int tid  = threadIdx.x;
    const int wave = tid >> 6;   // 0..9
    const int lane = tid & 63;

    // ---- Phase A / sim-finish / Phase D mapping ----
    const bool lower = tid < 320;
    const int cA     = lower ? tid : (tid - 320);
    const bool actA  = cA < HDIM;

    // ---- Phase B mapping: 4 j-groups x 150 column-pairs ----
    const bool actB = tid < 600;
    const int  gB   = tid / 150;          // j-group 0..3 (4 for inactive; unused)
    const int  pB   = tid % 150;          // column-pair index
    const int  jb   = gB * 5;             // j-base
    const int  c0   = 2 * pB;             // columns c0, c0+1

    // ---- init state ----
    for (int idx = tid; idx < M * HDIM; idx += 640) ((float*)sh_mem)[idx] = 0.0f;
    if (tid < M) sh_usage[tid] = 0.0f;

    const float be2v = be2[0];
    const float bs2v = bs2[0];
    // step-invariant per-column scalars
    float bs1c = 0.f, be1c = 0.f, we2c = 0.f, ws2c = 0.f, w900c = 0.f, buc = 0.f;
    if (actA) {
        if (lower) {
            bs1c = bs1[cA]; be1c = be1[cA]; we2c = We2[cA];
            ws2c = Ws2[cA]; w900c = Ws1[900 * 300 + cA];
        } else {
            buc = bu[cA];
        }
    }
    __syncthreads();

    for (int t = 0; t < T_STEPS; ++t) {
        const int tb = t * BATCH + b;

        // ---- load h (upper half) ----
        if (!lower && actA) sh_h[cA] = hs[(size_t)tb * HDIM + cA];
        __syncthreads();   // (1) h ready; prev step fully done

        // ---- Phase A: h-GEMVs (hb1, hwu in registers; ent partials) ----
        float hb1reg = 0.f, hwureg = 0.f;
        {
            float a1 = 0.f, ae = 0.f, au = 0.f;
            if (actA) {
                if (lower) {
                    const float* pB_ = Ws1 + 90000 + cA;  // rows 300..599
                    const float* pE  = We1 + cA;
                    for (int k = 0; k < HDIM; k += 4) {
                        float4 h4 = *(const float4*)&sh_h[k];
                        const float* q  = pB_ + k * 300;
                        const float* qe = pE + k * 300;
                        a1 += h4.x * q[0] + h4.y * q[300] + h4.z * q[600] + h4.w * q[900];
                        ae += h4.x * qe[0] + h4.y * qe[300] + h4.z * qe[600] + h4.w * qe[900];
                    }
                } else {
                    const float* pU = Wu + cA;            // rows 0..299
                    for (int k = 0; k < HDIM; k += 4) {
                        float4 h4 = *(const float4*)&sh_h[k];
                        const float* q = pU + k * 300;
                        au += h4.x * q[0] + h4.y * q[300] + h4.z * q[600] + h4.w * q[900];
                    }
                }
            }
            if (lower) {
                float er = actA ? (fmaxf(ae + be1c, 0.0f) * we2c) : 0.0f;
                for (int off = 32; off; off >>= 1) er += __shfl_xor(er, off, 64);
                if (lane == 0) sh_entpart[wave] = er;
                hb1reg = a1 + bs1c;
            } else {
                hwureg = au + buc;
            }
        }

        // ---- Phase B: fused sim+cand, 2 cols x 5 j's x full K per thread ----
#define DECL_ACC(jj) float aS0_##jj = 0.f, aS1_##jj = 0.f, aC0_##jj = 0.f, aC1_##jj = 0.f;
        FOR5(DECL_ACC)
#undef DECL_ACC

        if (actB) {
            const float* qa = Ws1 + c0;            // rows 0..299   (mem)
            const float* qc = Ws1 + 180000 + c0;   // rows 600..899 (h*mem)
            const float* qu = Wu + 90000 + c0;     // rows 300..599 (mem)
            // preload k=0 weight block (12 float2)
            float2 A0 = *(const float2*)(qa);
            float2 A1 = *(const float2*)(qa + 300);
            float2 A2 = *(const float2*)(qa + 600);
            float2 A3 = *(const float2*)(qa + 900);
            float2 C0 = *(const float2*)(qc);
            float2 C1 = *(const float2*)(qc + 300);
            float2 C2 = *(const float2*)(qc + 600);
            float2 C3 = *(const float2*)(qc + 900);
            float2 U0 = *(const float2*)(qu);
            float2 U1 = *(const float2*)(qu + 300);
            float2 U2 = *(const float2*)(qu + 600);
            float2 U3 = *(const float2*)(qu + 900);
            for (int k = 0; k < HDIM; k += 4) {
                // prefetch next iteration's weights (clamped in-bounds; last
                // iteration harmlessly re-reads k=0)
                const int kn = (k + 4 < HDIM) ? (k + 4) : 0;
                const float* na = qa + kn * 300;
                const float* nc = qc + kn * 300;
                const float* nu = qu + kn * 300;
                float2 NA0 = *(const float2*)(na);
                float2 NA1 = *(const float2*)(na + 300);
                float2 NA2 = *(const float2*)(na + 600);
                float2 NA3 = *(const float2*)(na + 900);
                float2 NC0 = *(const float2*)(nc);
                float2 NC1 = *(const float2*)(nc + 300);
                float2 NC2 = *(const float2*)(nc + 600);
                float2 NC3 = *(const float2*)(nc + 900);
                float2 NU0 = *(const float2*)(nu);
                float2 NU1 = *(const float2*)(nu + 300);
                float2 NU2 = *(const float2*)(nu + 600);
                float2 NU3 = *(const float2*)(nu + 900);

                float4 h4 = *(const float4*)&sh_h[k];
                float w00 = fmaf(h4.x, C0.x, A0.x);
                float w01 = fmaf(h4.y, C1.x, A1.x);
                float w02 = fmaf(h4.z, C2.x, A2.x);
                float w03 = fmaf(h4.w, C3.x, A3.x);
                float w10 = fmaf(h4.x, C0.y, A0.y);
                float w11 = fmaf(h4.y, C1.y, A1.y);
                float w12 = fmaf(h4.z, C2.y, A2.y);
                float w13 = fmaf(h4.w, C3.y, A3.y);
#define ACC_J(jj) { \
                float4 mv = *(const float4*)&sh_mem[jb + jj][k]; \
                aS0_##jj += mv.x * w00 + mv.y * w01 + mv.z * w02 + mv.w * w03; \
                aS1_##jj += mv.x * w10 + mv.y * w11 + mv.z * w12 + mv.w * w13; \
                aC0_##jj += mv.x * U0.x + mv.y * U1.x + mv.z * U2.x + mv.w * U3.x; \
                aC1_##jj += mv.x * U0.y + mv.y * U1.y + mv.z * U2.y + mv.w * U3.y; }
                FOR5(ACC_J)
#undef ACC_J
                A0 = NA0; A1 = NA1; A2 = NA2; A3 = NA3;
                C0 = NC0; C1 = NC1; C2 = NC2; C3 = NC3;
                U0 = NU0; U1 = NU1; U2 = NU2; U3 = NU3;
            }
#define WB(jj) { \
            *(float2*)&sh_sim[jb + jj][c0]  = make_float2(aS0_##jj, aS1_##jj); \
            *(float2*)&sh_cand[jb + jj][c0] = make_float2(aC0_##jj, aC1_##jj); }
            FOR5(WB)
#undef WB
        }
        __syncthreads();   // (2) sim/cand partials complete

        // ---- sim finish: relu(.)*Ws2, reduce over columns (lower waves) ----
        if (lower) {
#pragma unroll
            for (int j = 0; j < M; ++j) {
                float v = 0.f;
                if (actA) {
                    float pre = sh_sim[j][cA] + hb1reg + sh_usage[j] * w900c;
                    v = fmaxf(pre, 0.0f) * ws2c;
                }
                for (int off = 32; off; off >>= 1) v += __shfl_xor(v, off, 64);
                if (lane == 0) sh_simpart[wave][j] = v;
            }
        }
        __syncthreads();   // (3)

        // ---- Phase C: decision (wave 0) ----
        if (wave == 0) {
            const bool act = lane < M;
            float simj = -INFINITY, usg = 0.0f;
            if (act) {
                float sv = sh_simpart[0][lane];
                sv += sh_simpart[1][lane];
                sv += sh_simpart[2][lane];
                sv += sh_simpart[3][lane];
                sv += sh_simpart[4][lane];
                simj = sv + bs2v;
                usg = sh_usage[lane];
            }
            float es = sh_entpart[0] + sh_entpart[1] + sh_entpart[2]
                     + sh_entpart[3] + sh_entpart[4] + be2v;
            const float entp = (1.0f / (1.0f + expf(-es))) * msk[tb];

            const float coref = (act && usg > 0.0f) ? 1.0f : 0.0f;
            float comb = act ? ((usg > 0.0f) ? simj : -10000.0f) : -INFINITY;
            float mx = comb;
            for (int off = 32; off; off >>= 1) mx = fmaxf(mx, __shfl_xor(mx, off, 64));
            mx = fmaxf(mx, 0.0f);
            float e = act ? expf(comb - mx) : 0.0f;
            const float eM = expf(0.0f - mx);
            float den = e;
            for (int off = 32; off; off >>= 1) den += __shfl_xor(den, off, 64);
            den += eM;
            const float prob  = e / den;
            const float probM = eM / den;
            float masked = prob * coref;
            float msum = masked;
            for (int off = 32; off; off >>= 1) msum += __shfl_xor(msum, off, 64);
            msum += probM;
            const float dn = msum + 1e-8f;
            const float normj = masked / dn;
            const float normM = probM / dn;
            const float indv = act ? (entp * normj) : 0.0f;
            const float ow_base = entp * normM;

            // nsim = softmax(sim)
            float nmx = simj;
            for (int off = 32; off; off >>= 1) nmx = fmaxf(nmx, __shfl_xor(nmx, off, 64));
            float ne = act ? expf(simj - nmx) : 0.0f;
            float ns = ne;
            for (int off = 32; off; off >>= 1) ns += __shfl_xor(ns, off, 64);
            const float nsim = ne / ns;

            float ows = act ? (((usg == 0.0f) ? nsim * 100000.0f : 0.0f) + (1.0f - usg))
                            : -INFINITY;
            float mv = ows;
            for (int off = 32; off; off >>= 1) mv = fmaxf(mv, __shfl_xor(mv, off, 64));

            float key = 0.0f;
            if (act && ows == mv) key = jax_noise((unsigned)(tb * M + lane));
            float bv = act ? key : -1.0f;
            int bi = act ? lane : 1023;
            for (int off = 32; off; off >>= 1) {
                float ov = __shfl_xor(bv, off, 64);
                int oi = __shfl_xor(bi, off, 64);
                if (ov > bv || (ov == bv && oi < bi)) { bv = ov; bi = oi; }
            }
            const float ow = (act && lane == bi) ? ow_base : 0.0f;
            const float nu = fminf(1.0f, (ow + indv) + 0.98f * usg);

            if (act) {
                sh_ow[lane] = ow;
                sh_indv[lane] = indv;
                sh_usage[lane] = nu;
                const int base = tb * M + lane;
                out[65536 + base]   = nu;                                   // usage_seq
                out[1376256 + base] = indv * (1.0f - 1e-8f) + 1e-8f;        // coref
                out[2686976 + base] = ow * (1.0f - 1e-8f) + 1e-8f;          // overwrite
            }
            if (lane == 0) out[tb] = entp * (1.0f - 1e-8f) + 1e-8f;          // ent
        }
        __syncthreads();   // (4)

        // ---- Phase D: memory update (upper half; cand = tanh(sum + hwu)) ----
        if (!lower && actA) {
            const float hc = sh_h[cA];
#pragma unroll
            for (int j = 0; j < M; ++j) {
                const float owj = sh_ow[j];
                const float inj = sh_indv[j];
                const float cd  = tanhf(sh_cand[j][cA] + hwureg);
                const float mo  = sh_mem[j][cA];
                sh_mem[j][cA] = owj * hc + (1.0f - owj - inj) * mo + inj * cd;
            }
        }
        __syncthreads();   // (5)
    }
}

extern "C" void kernel_launch(void* const* d_in, const int* in_sizes, int n_in,
                              void* d_out, int out_size, void* d_ws, size_t ws_size,
                              hipStream_t stream) {
    (void)in_sizes; (void)n_in; (void)d_ws; (void)ws_size; (void)out_size;
    const float* hs  = (const float*)d_in[0];
    const float* msk = (const float*)d_in[1];
    const float* We1 = (const float*)d_in[2];
    const float* be1 = (const float*)d_in[3];
    const float* We2 = (const float*)d_in[4];
    const float* be2 = (const float*)d_in[5];
    const float* Ws1 = (const float*)d_in[6];
    const float* bs1 = (const float*)d_in[7];
    const float* Ws2 = (const float*)d_in[8];
    const float* bs2 = (const float*)d_in[9];
    const float* Wu  = (const float*)d_in[10];
    const float* bu  = (const float*)d_in[11];
    float* out = (float*)d_out;

    hipLaunchKernelGGL(wm_kernel, dim3(BATCH), dim3(640), 0, stream,
                       hs, msk, We1, be1, We2, be2, Ws1, bs1, Ws2, bs2, Wu, bu, out);
}

// Round 6
// 23159.300 us; speedup vs baseline: 4.1060x; 1.8614x over previous
//
#include <hip/hip_runtime.h>
#include <math.h>

#define T_STEPS 512
#define BATCH   128
#define HDIM    300
#define M       20
#define M2      10   // j's owned per block

// ---------------- JAX threefry2x32 noise replication ----------------
__device__ __forceinline__ unsigned rotl32(unsigned v, int r) {
    return (v << r) | (v >> (32 - r));
}

__device__ float jax_noise(unsigned i) {
#pragma clang fp contract(off)
    unsigned x0 = 0u;
    unsigned x1 = i;
    const unsigned ks0 = 0u, ks1 = 42u, ks2 = 0u ^ 42u ^ 0x1BD11BDAu;
    x0 += ks0; x1 += ks1;
    x0 += x1; x1 = rotl32(x1, 13); x1 ^= x0;
    x0 += x1; x1 = rotl32(x1, 15); x1 ^= x0;
    x0 += x1; x1 = rotl32(x1, 26); x1 ^= x0;
    x0 += x1; x1 = rotl32(x1, 6);  x1 ^= x0;
    x0 += ks1; x1 += ks2 + 1u;
    x0 += x1; x1 = rotl32(x1, 17); x1 ^= x0;
    x0 += x1; x1 = rotl32(x1, 29); x1 ^= x0;
    x0 += x1; x1 = rotl32(x1, 16); x1 ^= x0;
    x0 += x1; x1 = rotl32(x1, 24); x1 ^= x0;
    x0 += ks2; x1 += ks0 + 2u;
    x0 += x1; x1 = rotl32(x1, 13); x1 ^= x0;
    x0 += x1; x1 = rotl32(x1, 15); x1 ^= x0;
    x0 += x1; x1 = rotl32(x1, 26); x1 ^= x0;
    x0 += x1; x1 = rotl32(x1, 6);  x1 ^= x0;
    x0 += ks0; x1 += ks1 + 3u;
    x0 += x1; x1 = rotl32(x1, 17); x1 ^= x0;
    x0 += x1; x1 = rotl32(x1, 29); x1 ^= x0;
    x0 += x1; x1 = rotl32(x1, 16); x1 ^= x0;
    x0 += x1; x1 = rotl32(x1, 24); x1 ^= x0;
    x0 += ks1; x1 += ks2 + 4u;
    x0 += x1; x1 = rotl32(x1, 13); x1 ^= x0;
    x0 += x1; x1 = rotl32(x1, 15); x1 ^= x0;
    x0 += x1; x1 = rotl32(x1, 26); x1 ^= x0;
    x0 += x1; x1 = rotl32(x1, 6);  x1 ^= x0;
    x0 += ks2; x1 += ks0 + 5u;

    const unsigned bits = x0 ^ x1;
    const unsigned fb = (bits >> 9) | 0x3f800000u;
    float f = __uint_as_float(fb) - 1.0f;
    const float span = 1.0f - 0.01f;
    float v = f * span;
    v = v + 0.01f;
    return fmaxf(0.01f, v);
}

#define FOR5(X) X(0) X(1) X(2) X(3) X(4)

// ---------------- paired persistent kernel ----------------
// grid = 256 blocks: block bid handles batch b = bid&127, j-half jhalf = bid>>7
// (j's jb2..jb2+9, jb2 = jhalf*10). Partner = bid^128 (same XCD under %8
// round-robin). Per step the ONLY cross-j coupling is softmax over the 20
// scalar sim[j] -> exchange 10 floats via L2 with agent-scope release/acquire.
// Phase A + Phase C computed redundantly on both halves (bitwise identical).
// Phase B (dominant GEMM) and Phase D halve per CU; all 256 CUs active.
// LDS ~37KB and ~70 VGPR => >=2 blocks/CU can co-reside in any packing =>
// all 256 blocks always resident => spin-wait cannot deadlock.
__global__ void __launch_bounds__(640, 3)
wm_kernel(const float* __restrict__ hs,   // (T,B,H)
          const float* __restrict__ msk,  // (T,B)
          const float* __restrict__ We1,  // (300,300)
          const float* __restrict__ be1,  // (300)
          const float* __restrict__ We2,  // (300,1)
          const float* __restrict__ be2,  // (1)
          const float* __restrict__ Ws1,  // (901,300)
          const float* __restrict__ bs1,  // (300)
          const float* __restrict__ Ws2,  // (300,1)
          const float* __restrict__ bs2,  // (1)
          const float* __restrict__ Wu,   // (600,300)
          const float* __restrict__ bu,   // (300)
          float* __restrict__ out,
          float* __restrict__ ws)         // d_ws: vals[256][16] @0, flags @+16KB
{
    __shared__ __align__(16) float sh_mem[M2][HDIM];
    __shared__ __align__(16) float sh_h[HDIM];
    __shared__ __align__(16) float sh_sim[M2][HDIM];
    __shared__ __align__(16) float sh_cand[M2][HDIM];
    __shared__ float sh_usage[M];         // all 20 (tracked redundantly)
    __shared__ float sh_simpart[5][M2];
    __shared__ float sh_entpart[5];
    __shared__ float sh_ow[M];
    __shared__ float sh_indv[M];

    const int bid   = blockIdx.x;
    const int b     = bid & 127;
    const int jhalf = bid >> 7;
    const int jb2   = jhalf * 10;         // own global j-base
    const int pbase = 10 - jb2;           // partner global j-base
    const int pbid  = bid ^ 128;

    float*    vals_me = ws + (size_t)bid * 16;
    float*    vals_p  = ws + (size_t)pbid * 16;
    unsigned* flag_me = (unsigned*)(ws + 4096) + (size_t)bid * 16;
    unsigned* flag_p  = (unsigned*)(ws + 4096) + (size_t)pbid * 16;

    const int tid  = threadIdx.x;
    const int wave = tid >> 6;   // 0..9
    const int lane = tid & 63;

    // ---- Phase A / sim-finish / Phase D mapping ----
    const bool lower = tid < 320;
    const int cA     = lower ? tid : (tid - 320);
    const bool actA  = cA < HDIM;

    // ---- Phase B mapping: 2 local j-groups (5 j's) x 300 columns ----
    const bool actB = tid < 600;
    const int  cB   = (tid < 300) ? tid : (tid - 300);
    const int  jl   = (tid < 300) ? 0 : 5;   // local j-base within our 10 rows

    // ---- init state ----
    for (int idx = tid; idx < M2 * HDIM; idx += 640) ((float*)sh_mem)[idx] = 0.0f;
    if (tid < M) sh_usage[tid] = 0.0f;

    const float be2v = be2[0];
    const float bs2v = bs2[0];
    // step-invariant per-column scalars
    float bs1c = 0.f, be1c = 0.f, we2c = 0.f, ws2c = 0.f, w900c = 0.f, buc = 0.f;
    if (actA) {
        if (lower) {
            bs1c = bs1[cA]; be1c = be1[cA]; we2c = We2[cA];
            ws2c = Ws2[cA]; w900c = Ws1[900 * 300 + cA];
        } else {
            buc = bu[cA];
        }
    }
    __syncthreads();

    for (int t = 0; t < T_STEPS; ++t) {
        const int tb = t * BATCH + b;

        // ---- load h (upper half) ----
        if (!lower && actA) sh_h[cA] = hs[(size_t)tb * HDIM + cA];
        __syncthreads();   // (1)

        // ---- Phase A: h-GEMVs (redundant on both halves) ----
        float hb1reg = 0.f, hwureg = 0.f;
        {
            float a1 = 0.f, ae = 0.f, au = 0.f;
            if (actA) {
                if (lower) {
                    const float* pB_ = Ws1 + 90000 + cA;  // rows 300..599
                    const float* pE  = We1 + cA;
                    for (int k = 0; k < HDIM; k += 4) {
                        float4 h4 = *(const float4*)&sh_h[k];
                        const float* q  = pB_ + k * 300;
                        const float* qe = pE + k * 300;
                        a1 += h4.x * q[0] + h4.y * q[300] + h4.z * q[600] + h4.w * q[900];
                        ae += h4.x * qe[0] + h4.y * qe[300] + h4.z * qe[600] + h4.w * qe[900];
                    }
                } else {
                    const float* pU = Wu + cA;            // rows 0..299
                    for (int k = 0; k < HDIM; k += 4) {
                        float4 h4 = *(const float4*)&sh_h[k];
                        const float* q = pU + k * 300;
                        au += h4.x * q[0] + h4.y * q[300] + h4.z * q[600] + h4.w * q[900];
                    }
                }
            }
            if (lower) {
                float er = actA ? (fmaxf(ae + be1c, 0.0f) * we2c) : 0.0f;
                for (int off = 32; off; off >>= 1) er += __shfl_xor(er, off, 64);
                if (lane == 0) sh_entpart[wave] = er;
                hb1reg = a1 + bs1c;
            } else {
                hwureg = au + buc;
            }
        }

        // ---- Phase B: fused sim+cand, 1 col x 5 local j's x full K ----
#define DECL_ACC(jj) float aS_##jj = 0.f, aC_##jj = 0.f;
        FOR5(DECL_ACC)
#undef DECL_ACC

        if (actB) {
            const float* qa = Ws1 + cB;            // rows 0..299   (mem)
            const float* qc = Ws1 + 180000 + cB;   // rows 600..899 (h*mem)
            const float* qu = Wu + 90000 + cB;     // rows 300..599 (mem)
            float A0 = qa[0], A1 = qa[300], A2 = qa[600], A3 = qa[900];
            float C0 = qc[0], C1 = qc[300], C2 = qc[600], C3 = qc[900];
            float U0 = qu[0], U1 = qu[300], U2 = qu[600], U3 = qu[900];
            for (int k = 0; k < HDIM; k += 4) {
                const int kn = (k + 4 < HDIM) ? (k + 4) : 0;   // clamped prefetch
                const float* na = qa + kn * 300;
                const float* nc = qc + kn * 300;
                const float* nu = qu + kn * 300;
                float NA0 = na[0], NA1 = na[300], NA2 = na[600], NA3 = na[900];
                float NC0 = nc[0], NC1 = nc[300], NC2 = nc[600], NC3 = nc[900];
                float NU0 = nu[0], NU1 = nu[300], NU2 = nu[600], NU3 = nu[900];

                float4 h4 = *(const float4*)&sh_h[k];
                float w0 = fmaf(h4.x, C0, A0);
                float w1 = fmaf(h4.y, C1, A1);
                float w2 = fmaf(h4.z, C2, A2);
                float w3 = fmaf(h4.w, C3, A3);
#define ACC_J(jj) { \
                float4 mv = *(const float4*)&sh_mem[jl + jj][k]; \
                aS_##jj += mv.x * w0 + mv.y * w1 + mv.z * w2 + mv.w * w3; \
                aC_##jj += mv.x * U0 + mv.y * U1 + mv.z * U2 + mv.w * U3; }
                FOR5(ACC_J)
#undef ACC_J
                A0 = NA0; A1 = NA1; A2 = NA2; A3 = NA3;
                C0 = NC0; C1 = NC1; C2 = NC2; C3 = NC3;
                U0 = NU0; U1 = NU1; U2 = NU2; U3 = NU3;
            }
#define WB(jj) { sh_sim[jl + jj][cB] = aS_##jj; sh_cand[jl + jj][cB] = aC_##jj; }
            FOR5(WB)
#undef WB
        }
        __syncthreads();   // (2)

        // ---- sim finish: relu(.)*Ws2, reduce over columns (lower waves, 10 j) ----
        if (lower) {
#pragma unroll
            for (int jj = 0; jj < M2; ++jj) {
                float v = 0.f;
                if (actA) {
                    float pre = sh_sim[jj][cA] + hb1reg + sh_usage[jb2 + jj] * w900c;
                    v = fmaxf(pre, 0.0f) * ws2c;
                }
                for (int off = 32; off; off >>= 1) v += __shfl_xor(v, off, 64);
                if (lane == 0) sh_simpart[wave][jj] = v;
            }
        }
        __syncthreads();   // (3)

        // ---- Phase C: exchange + decision (wave 0; redundant on both halves) ----
        if (wave == 0) {
            // final own sim values (no bias yet), lanes 0..9
            float sown = 0.f;
            if (lane < M2) {
                sown = sh_simpart[0][lane] + sh_simpart[1][lane] + sh_simpart[2][lane]
                     + sh_simpart[3][lane] + sh_simpart[4][lane];
                __hip_atomic_store(&vals_me[lane], sown, __ATOMIC_RELAXED,
                                   __HIP_MEMORY_SCOPE_AGENT);
            }
            if (lane == 0) {
                // release waits for the wave's outstanding stores (vmcnt) first
                __hip_atomic_store(flag_me, (unsigned)(t + 1), __ATOMIC_RELEASE,
                                   __HIP_MEMORY_SCOPE_AGENT);
                while (__hip_atomic_load(flag_p, __ATOMIC_ACQUIRE,
                                         __HIP_MEMORY_SCOPE_AGENT) < (unsigned)(t + 1))
                    __builtin_amdgcn_s_sleep(1);
            }
            float pvv = 0.f;
            if (lane >= pbase && lane < pbase + M2)
                pvv = __hip_atomic_load(&vals_p[lane - pbase], __ATOMIC_ACQUIRE,
                                        __HIP_MEMORY_SCOPE_AGENT);
            const float myv = __shfl(sown, lane - jb2, 64);

            const bool act = lane < M;
            const bool own = act && (lane >= jb2) && (lane < jb2 + M2);
            float simj = -INFINITY, usg = 0.0f;
            if (act) {
                simj = (own ? myv : pvv) + bs2v;
                usg  = sh_usage[lane];
            }
            float es = sh_entpart[0] + sh_entpart[1] + sh_entpart[2]
                     + sh_entpart[3] + sh_entpart[4] + be2v;
            const float entp = (1.0f / (1.0f + expf(-es))) * msk[tb];

            const float coref = (act && usg > 0.0f) ? 1.0f : 0.0f;
            float comb = act ? ((usg > 0.0f) ? simj : -10000.0f) : -INFINITY;
            float mx = comb;
            for (int off = 32; off; off >>= 1) mx = fmaxf(mx, __shfl_xor(mx, off, 64));
            mx = fmaxf(mx, 0.0f);
            float e = act ? expf(comb - mx) : 0.0f;
            const float eM = expf(0.0f - mx);
            float den = e;
            for (int off = 32; off; off >>= 1) den += __shfl_xor(den, off, 64);
            den += eM;
            const float prob  = e / den;
            const float probM = eM / den;
            float masked = prob * coref;
            float msum = masked;
            for (int off = 32; off; off >>= 1) msum += __shfl_xor(msum, off, 64);
            msum += probM;
            const float dn = msum + 1e-8f;
            const float normj = masked / dn;
            const float normM = probM / dn;
            const float indv = act ? (entp * normj) : 0.0f;
            const float ow_base = entp * normM;

            // nsim = softmax(sim)
            float nmx = simj;
            for (int off = 32; off; off >>= 1) nmx = fmaxf(nmx, __shfl_xor(nmx, off, 64));
            float ne = act ? expf(simj - nmx) : 0.0f;
            float ns = ne;
            for (int off = 32; off; off >>= 1) ns += __shfl_xor(ns, off, 64);
            const float nsim = ne / ns;

            float ows = act ? (((usg == 0.0f) ? nsim * 100000.0f : 0.0f) + (1.0f - usg))
                            : -INFINITY;
            float mv = ows;
            for (int off = 32; off; off >>= 1) mv = fmaxf(mv, __shfl_xor(mv, off, 64));

            float key = 0.0f;
            if (act && ows == mv) key = jax_noise((unsigned)(tb * M + lane));
            float bv = act ? key : -1.0f;
            int bi = act ? lane : 1023;
            for (int off = 32; off; off >>= 1) {
                float ov = __shfl_xor(bv, off, 64);
                int oi = __shfl_xor(bi, off, 64);
                if (ov > bv || (ov == bv && oi < bi)) { bv = ov; bi = oi; }
            }
            const float ow = (act && lane == bi) ? ow_base : 0.0f;
            const float nu = fminf(1.0f, (ow + indv) + 0.98f * usg);

            if (act) {
                sh_ow[lane] = ow;
                sh_indv[lane] = indv;
                sh_usage[lane] = nu;
            }
            if (own) {
                const int base = tb * M + lane;
                out[65536 + base]   = nu;                                   // usage_seq
                out[1376256 + base] = indv * (1.0f - 1e-8f) + 1e-8f;        // coref
                out[2686976 + base] = ow * (1.0f - 1e-8f) + 1e-8f;          // overwrite
            }
            if (jhalf == 0 && lane == 0) out[tb] = entp * (1.0f - 1e-8f) + 1e-8f; // ent
        }
        __syncthreads();   // (4)

        // ---- Phase D: memory update (upper half; own 10 j's) ----
        if (!lower && actA) {
            const float hc = sh_h[cA];
#pragma unroll
            for (int jj = 0; jj < M2; ++jj) {
                const float owj = sh_ow[jb2 + jj];
                const float inj = sh_indv[jb2 + jj];
                const float cd  = tanhf(sh_cand[jj][cA] + hwureg);
                const float mo  = sh_mem[jj][cA];
                sh_mem[jj][cA] = owj * hc + (1.0f - owj - inj) * mo + inj * cd;
            }
        }
        __syncthreads();   // (5)
    }
}

extern "C" void kernel_launch(void* const* d_in, const int* in_sizes, int n_in,
                              void* d_out, int out_size, void* d_ws, size_t ws_size,
                              hipStream_t stream) {
    (void)in_sizes; (void)n_in; (void)ws_size; (void)out_size;
    const float* hs  = (const float*)d_in[0];
    const float* msk = (const float*)d_in[1];
    const float* We1 = (const float*)d_in[2];
    const float* be1 = (const float*)d_in[3];
    const float* We2 = (const float*)d_in[4];
    const float* be2 = (const float*)d_in[5];
    const float* Ws1 = (const float*)d_in[6];
    const float* bs1 = (const float*)d_in[7];
    const float* Ws2 = (const float*)d_in[8];
    const float* bs2 = (const float*)d_in[9];
    const float* Wu  = (const float*)d_in[10];
    const float* bu  = (const float*)d_in[11];
    float* out = (float*)d_out;

    // zero the sync flags/vals (stream-ordered, graph-capturable)
    hipMemsetAsync(d_ws, 0, 64 * 1024, stream);
    hipLaunchKernelGGL(wm_kernel, dim3(256), dim3(640), 0, stream,
                       hs, msk, We1, be1, We2, be2, Ws1, bs1, Ws2, bs2, Wu, bu,
                       out, (float*)d_ws);
}